// Round 1
// baseline (1814.757 us; speedup 1.0000x reference)
//
#include <hip/hip_runtime.h>

#define N_NODES 4096
#define C_DIM   128
#define L_LAYERS 4
#define E_EDGES 131072
#define H_HEADS 4
#define D_HEAD  32
#define NC      (N_NODES * C_DIM)

typedef short bf16x8 __attribute__((ext_vector_type(8)));
typedef float f32x4  __attribute__((ext_vector_type(4)));

__device__ __forceinline__ unsigned short f2bf(float f) {
    unsigned int u = __float_as_uint(f);
    u += 0x7fffu + ((u >> 16) & 1u);
    return (unsigned short)(u >> 16);
}

__device__ __forceinline__ bf16x8 pack8(const float* v) {
    bf16x8 o;
#pragma unroll
    for (int i = 0; i < 8; ++i) o[i] = (short)f2bf(v[i]);
    return o;
}

// ---------------------------------------------------------------------------
// GIN scatter-add aggregation: agg[dst] += x[src]  (fp32 atomics)
// thread t: edge e = t>>5, channel-quad cq = t&31
// ---------------------------------------------------------------------------
__global__ __launch_bounds__(256) void scatter_add(const float* __restrict__ x,
                                                   const int* __restrict__ ei,
                                                   float* __restrict__ agg) {
    int t  = blockIdx.x * 256 + threadIdx.x;
    int e  = t >> 5;
    int cq = t & 31;
    int s  = ei[e];
    int d  = ei[E_EDGES + e];
    float4 v = *(const float4*)(x + (size_t)s * C_DIM + cq * 4);
    float* a = agg + (size_t)d * C_DIM + cq * 4;
    atomicAdd(a + 0, v.x);
    atomicAdd(a + 1, v.y);
    atomicAdd(a + 2, v.z);
    atomicAdd(a + 3, v.w);
}

// ---------------------------------------------------------------------------
// fp32 GEMM: out[n][j] = act( sum_k (A[n][k] (+A2[n][k])) * W[j][k] + bias[j]
//                             (+ resid[n][j]) )
// tile 64 rows x 64 cols, 256 threads, 4x4 micro-tile. grid (J/64, N/64).
// ---------------------------------------------------------------------------
template <int K>
__global__ __launch_bounds__(256) void gemm_f32(const float* __restrict__ A,
                                                const float* __restrict__ A2,
                                                const float* __restrict__ W,
                                                const float* __restrict__ bias,
                                                const float* __restrict__ resid,
                                                float* __restrict__ out,
                                                const int J, const int relu) {
    __shared__ __align__(16) float As[64 * 132];
    __shared__ __align__(16) float Ws[64 * 132];
    const int tid = threadIdx.x;
    const int ct = blockIdx.x, rt = blockIdx.y;
    const int tc = tid & 15, tr = tid >> 4;
    float acc[4][4] = {};

    for (int kc = 0; kc < K; kc += 128) {
        if (kc) __syncthreads();
#pragma unroll
        for (int i = 0; i < 8; ++i) {
            int idx = tid + i * 256;
            int r = idx >> 5, kq = idx & 31;
            float4 av = *(const float4*)(A + (size_t)(rt * 64 + r) * K + kc + kq * 4);
            if (A2) {
                float4 t2 = *(const float4*)(A2 + (size_t)(rt * 64 + r) * K + kc + kq * 4);
                av.x += t2.x; av.y += t2.y; av.z += t2.z; av.w += t2.w;
            }
            *(float4*)(As + r * 132 + kq * 4) = av;
            float4 wv = *(const float4*)(W + (size_t)(ct * 64 + r) * K + kc + kq * 4);
            *(float4*)(Ws + r * 132 + kq * 4) = wv;
        }
        __syncthreads();
#pragma unroll 4
        for (int k4 = 0; k4 < 32; ++k4) {
            float4 a[4], w[4];
#pragma unroll
            for (int i = 0; i < 4; ++i) a[i] = *(const float4*)(As + (tr * 4 + i) * 132 + k4 * 4);
#pragma unroll
            for (int j = 0; j < 4; ++j) w[j] = *(const float4*)(Ws + (tc * 4 + j) * 132 + k4 * 4);
#pragma unroll
            for (int i = 0; i < 4; ++i)
#pragma unroll
                for (int j = 0; j < 4; ++j)
                    acc[i][j] += a[i].x * w[j].x + a[i].y * w[j].y +
                                 a[i].z * w[j].z + a[i].w * w[j].w;
        }
    }

#pragma unroll
    for (int i = 0; i < 4; ++i) {
        int row = rt * 64 + tr * 4 + i;
        float4 o4;
        float* po = (float*)&o4;
#pragma unroll
        for (int j = 0; j < 4; ++j) {
            int col = ct * 64 + tc * 4 + j;
            float v = acc[i][j] + bias[col];
            if (resid) v += resid[(size_t)row * J + col];
            if (relu) v = fmaxf(v, 0.f);
            po[j] = v;
        }
        *(float4*)(out + (size_t)row * J + ct * 64 + tc * 4) = o4;
    }
}

// ---------------------------------------------------------------------------
// Flash attention, bf16 MFMA 16x16x32. grid (N/64, H), 256 threads (4 waves).
// Each wave owns 16 q-rows (one MFMA A fragment). 128-key tiles in LDS.
// Assumed input frag layout (k-permutation-invariant): A row = lane&15,
// B col = lane&15, k = 8*(lane>>4)+i.  D (verified m89): col = lane&15,
// row = (lane>>4)*4 + reg.
// ---------------------------------------------------------------------------
__global__ __launch_bounds__(256) void attn_kernel(const float* __restrict__ qkv,
                                                   float* __restrict__ o_out) {
    __shared__ __align__(16) unsigned short Kl[128 * 32];       // [key][d]
    __shared__ __align__(16) unsigned short Vl[32 * 136];       // [d][key] padded
    __shared__ __align__(16) unsigned short Pl[4 * 16 * 72];    // per-wave [16 q][72]

    const int h   = blockIdx.y;
    const int q0  = blockIdx.x * 64;
    const int tid = threadIdx.x;
    const int wv  = tid >> 6;
    const int lane = tid & 63;
    const int lg  = lane >> 4;
    const int ll  = lane & 15;

    // Q fragment, pre-scaled by (1/sqrt(d)) * log2(e)
    bf16x8 qf;
    {
        const float* qp = qkv + (size_t)(q0 + wv * 16 + ll) * (3 * C_DIM) + h * D_HEAD + lg * 8;
        float tmp[8];
        const float sc = 0.25506973f;
#pragma unroll
        for (int i = 0; i < 8; ++i) tmp[i] = qp[i] * sc;
        qf = pack8(tmp);
    }

    f32x4 oacc0 = {0.f, 0.f, 0.f, 0.f};
    f32x4 oacc1 = {0.f, 0.f, 0.f, 0.f};
    float m_r[4], l_r[4];
#pragma unroll
    for (int r = 0; r < 4; ++r) { m_r[r] = -1e30f; l_r[r] = 0.f; }

    unsigned short* Pw = Pl + wv * (16 * 72);

    for (int t = 0; t < N_NODES / 128; ++t) {
        __syncthreads();
        {   // stage K (row-major bf16) and V (transposed bf16)
            const int key = tid >> 1, hf = (tid & 1) * 16;
            const float* kp = qkv + (size_t)(t * 128 + key) * (3 * C_DIM) + C_DIM + h * D_HEAD + hf;
            const float* vp = kp + C_DIM;
            float kb[16];
#pragma unroll
            for (int i = 0; i < 16; ++i) kb[i] = kp[i];
            *(bf16x8*)(Kl + key * 32 + hf)     = pack8(kb);
            *(bf16x8*)(Kl + key * 32 + hf + 8) = pack8(kb + 8);
#pragma unroll
            for (int i = 0; i < 16; ++i) Vl[(hf + i) * 136 + key] = f2bf(vp[i]);
        }
        __syncthreads();

        // S = Q K^T over 128 keys (8 MFMAs)
        float s[8][4];
#pragma unroll
        for (int kc = 0; kc < 8; ++kc) {
            bf16x8 kf = *(const bf16x8*)(Kl + (kc * 16 + ll) * 32 + lg * 8);
            f32x4 z = {0.f, 0.f, 0.f, 0.f};
            f32x4 d = __builtin_amdgcn_mfma_f32_16x16x32_bf16(qf, kf, z, 0, 0, 0);
#pragma unroll
            for (int r = 0; r < 4; ++r) s[kc][r] = d[r];
        }

        // online softmax (rows reduced over 16 lanes sharing lg)
        float alpha[4];
#pragma unroll
        for (int r = 0; r < 4; ++r) {
            float mx = s[0][r];
#pragma unroll
            for (int kc = 1; kc < 8; ++kc) mx = fmaxf(mx, s[kc][r]);
#pragma unroll
            for (int off = 1; off < 16; off <<= 1) mx = fmaxf(mx, __shfl_xor(mx, off, 64));
            float mn = fmaxf(m_r[r], mx);
            alpha[r] = exp2f(m_r[r] - mn);
            m_r[r] = mn;
        }
#pragma unroll
        for (int r = 0; r < 4; ++r) {
            float ls = 0.f;
#pragma unroll
            for (int kc = 0; kc < 8; ++kc) {
                float p = exp2f(s[kc][r] - m_r[r]);
                s[kc][r] = p;
                ls += p;
            }
#pragma unroll
            for (int off = 1; off < 16; off <<= 1) ls += __shfl_xor(ls, off, 64);
            l_r[r] = l_r[r] * alpha[r] + ls;
            oacc0[r] *= alpha[r];
            oacc1[r] *= alpha[r];
        }

        // write P (bf16) to wave-private LDS: P[q = lg*4+r][key = kc*16+ll]
#pragma unroll
        for (int kc = 0; kc < 8; ++kc)
#pragma unroll
            for (int r = 0; r < 4; ++r)
                Pw[(lg * 4 + r) * 72 + kc * 16 + ll] = f2bf(s[kc][r]);
        asm volatile("" ::: "memory");   // same-wave DS ops are in-order

        // O += P @ V  (8 MFMAs)
#pragma unroll
        for (int kc2 = 0; kc2 < 4; ++kc2) {
            bf16x8 pf  = *(const bf16x8*)(Pw + ll * 72 + kc2 * 32 + lg * 8);
            bf16x8 vf0 = *(const bf16x8*)(Vl + (ll)      * 136 + kc2 * 32 + lg * 8);
            bf16x8 vf1 = *(const bf16x8*)(Vl + (16 + ll) * 136 + kc2 * 32 + lg * 8);
            oacc0 = __builtin_amdgcn_mfma_f32_16x16x32_bf16(pf, vf0, oacc0, 0, 0, 0);
            oacc1 = __builtin_amdgcn_mfma_f32_16x16x32_bf16(pf, vf1, oacc1, 0, 0, 0);
        }
    }

#pragma unroll
    for (int r = 0; r < 4; ++r) {
        int n = q0 + wv * 16 + lg * 4 + r;
        float inv = 1.f / l_r[r];
        o_out[(size_t)n * C_DIM + h * D_HEAD + ll]      = oacc0[r] * inv;
        o_out[(size_t)n * C_DIM + h * D_HEAD + 16 + ll] = oacc1[r] * inv;
    }
}

// ---------------------------------------------------------------------------
// BatchNorm stats: per-channel scale/shift.  grid 32 (4 channels/block).
// ss[c] = g*rstd ; ss[C+c] = b - mean*scale
// ---------------------------------------------------------------------------
__global__ __launch_bounds__(256) void bn_stats(const float* __restrict__ in,
                                                const float* __restrict__ g,
                                                const float* __restrict__ b,
                                                float* __restrict__ ss) {
    const int c4 = blockIdx.x;
    const int tid = threadIdx.x;
    float s[4] = {0.f, 0.f, 0.f, 0.f}, s2[4] = {0.f, 0.f, 0.f, 0.f};
    for (int r = tid; r < N_NODES; r += 256) {
        float4 v = *(const float4*)(in + (size_t)r * C_DIM + c4 * 4);
        s[0] += v.x; s2[0] += v.x * v.x;
        s[1] += v.y; s2[1] += v.y * v.y;
        s[2] += v.z; s2[2] += v.z * v.z;
        s[3] += v.w; s2[3] += v.w * v.w;
    }
#pragma unroll
    for (int off = 1; off < 64; off <<= 1) {
#pragma unroll
        for (int c = 0; c < 4; ++c) {
            s[c]  += __shfl_xor(s[c],  off, 64);
            s2[c] += __shfl_xor(s2[c], off, 64);
        }
    }
    __shared__ float red[4][8];
    int w = tid >> 6;
    if ((tid & 63) == 0) {
#pragma unroll
        for (int c = 0; c < 4; ++c) { red[w][c] = s[c]; red[w][4 + c] = s2[c]; }
    }
    __syncthreads();
    if (tid == 0) {
#pragma unroll
        for (int c = 0; c < 4; ++c) {
            float fs = red[0][c] + red[1][c] + red[2][c] + red[3][c];
            float fs2 = red[0][4 + c] + red[1][4 + c] + red[2][4 + c] + red[3][4 + c];
            int ch = c4 * 4 + c;
            float mean = fs / N_NODES;
            float var = fs2 / N_NODES - mean * mean;
            float rstd = rsqrtf(var + 1e-5f);
            float scale = g[ch] * rstd;
            ss[ch] = scale;
            ss[C_DIM + ch] = b[ch] - mean * scale;
        }
    }
}

// h = bn1(g1) + bn2(a2)
__global__ __launch_bounds__(256) void combine2(const float* __restrict__ p1,
                                                const float* __restrict__ p2,
                                                const float* __restrict__ ss1,
                                                const float* __restrict__ ss2,
                                                float* __restrict__ out) {
    int idx = blockIdx.x * 256 + threadIdx.x;   // NC/4 total
    int c4 = (idx & 31) * 4;
    float4 v1 = ((const float4*)p1)[idx];
    float4 v2 = ((const float4*)p2)[idx];
    float4 sc1 = *(const float4*)(ss1 + c4), sh1 = *(const float4*)(ss1 + C_DIM + c4);
    float4 sc2 = *(const float4*)(ss2 + c4), sh2 = *(const float4*)(ss2 + C_DIM + c4);
    float4 o;
    o.x = v1.x * sc1.x + sh1.x + v2.x * sc2.x + sh2.x;
    o.y = v1.y * sc1.y + sh1.y + v2.y * sc2.y + sh2.y;
    o.z = v1.z * sc1.z + sh1.z + v2.z * sc2.z + sh2.z;
    o.w = v1.w * sc1.w + sh1.w + v2.w * sc2.w + sh2.w;
    ((float4*)out)[idx] = o;
}

__global__ __launch_bounds__(256) void bn_apply(const float* __restrict__ p,
                                                const float* __restrict__ ss,
                                                float* __restrict__ out) {
    int idx = blockIdx.x * 256 + threadIdx.x;
    int c4 = (idx & 31) * 4;
    float4 v = ((const float4*)p)[idx];
    float4 sc = *(const float4*)(ss + c4), sh = *(const float4*)(ss + C_DIM + c4);
    float4 o;
    o.x = v.x * sc.x + sh.x;
    o.y = v.y * sc.y + sh.y;
    o.z = v.z * sc.z + sh.z;
    o.w = v.w * sc.w + sh.w;
    ((float4*)out)[idx] = o;
}

// head layers 2+3 fused: one thread per node
__global__ __launch_bounds__(256) void head23(const float* __restrict__ hh1,
                                              const float* __restrict__ w2,
                                              const float* __restrict__ b2,
                                              const float* __restrict__ w3,
                                              const float* __restrict__ b3,
                                              float* __restrict__ out) {
    int n = blockIdx.x * 256 + threadIdx.x;
    float4 r[16];
#pragma unroll
    for (int q = 0; q < 16; ++q) r[q] = *(const float4*)(hh1 + (size_t)n * 64 + q * 4);
    float acc = b3[0];
#pragma unroll 4
    for (int j = 0; j < 32; ++j) {
        float sv = b2[j];
#pragma unroll
        for (int q = 0; q < 16; ++q) {
            float4 wr = *(const float4*)(w2 + j * 64 + q * 4);
            sv += r[q].x * wr.x + r[q].y * wr.y + r[q].z * wr.z + r[q].w * wr.w;
        }
        acc += fmaxf(sv, 0.f) * w3[j];
    }
    out[n] = acc;
}

// ---------------------------------------------------------------------------
extern "C" void kernel_launch(void* const* d_in, const int* in_sizes, int n_in,
                              void* d_out, int out_size, void* d_ws, size_t ws_size,
                              hipStream_t stream) {
    (void)in_sizes; (void)n_in; (void)out_size; (void)ws_size;
    const float* x_in   = (const float*)d_in[0];
    const int*   ei     = (const int*)d_in[1];
    const float* gin_w1 = (const float*)d_in[2];
    const float* gin_b1 = (const float*)d_in[3];
    const float* gin_w2 = (const float*)d_in[4];
    const float* gin_b2 = (const float*)d_in[5];
    const float* ain_w  = (const float*)d_in[6];
    const float* ain_b  = (const float*)d_in[7];
    const float* aout_w = (const float*)d_in[8];
    const float* aout_b = (const float*)d_in[9];
    const float* n1_g   = (const float*)d_in[10];
    const float* n1_b   = (const float*)d_in[11];
    const float* n2_g   = (const float*)d_in[12];
    const float* n2_b   = (const float*)d_in[13];
    const float* n3_g   = (const float*)d_in[14];
    const float* n3_b   = (const float*)d_in[15];
    const float* mlp_w1 = (const float*)d_in[16];
    const float* mlp_b1 = (const float*)d_in[17];
    const float* mlp_w2 = (const float*)d_in[18];
    const float* mlp_b2 = (const float*)d_in[19];
    const float* h_w1   = (const float*)d_in[20];
    const float* h_b1   = (const float*)d_in[21];
    const float* h_w2   = (const float*)d_in[22];
    const float* h_b2   = (const float*)d_in[23];
    const float* h_w3   = (const float*)d_in[24];
    const float* h_b3   = (const float*)d_in[25];

    float* f = (float*)d_ws;
    float* agg    = f;                       // chunk 0 (also attn_o)
    float* t1     = f + 1 * (size_t)NC;      // chunk 1 (t2 spans chunks 1-2)
    float* g1     = f + 2 * (size_t)NC;      // chunk 2
    float* t2     = t1;
    float* qkv    = f + 3 * (size_t)NC;      // chunks 3-5
    float* a2     = f + 3 * (size_t)NC;      // chunk 3 (qkv dead by then)
    float* hbuf   = f + 4 * (size_t)NC;      // chunk 4
    float* m3     = f + 5 * (size_t)NC;      // chunk 5
    float* xA     = f + 6 * (size_t)NC;      // chunk 6
    float* xB     = f + 7 * (size_t)NC;      // chunk 7
    float* hh1    = f + 8 * (size_t)NC;      // N*64
    float* ss     = f + 8 * (size_t)NC + (size_t)N_NODES * 64;  // 3 * 256 floats
    float* attn_o = agg;

    for (int i = 0; i < L_LAYERS; ++i) {
        const float* xin = (i == 0) ? x_in : ((i & 1) ? xA : xB);
        float* xout = (i & 1) ? xB : xA;
        const float* gw1 = gin_w1 + (size_t)i * C_DIM * C_DIM;
        const float* gb1 = gin_b1 + (size_t)i * C_DIM;
        const float* gw2 = gin_w2 + (size_t)i * C_DIM * C_DIM;
        const float* gb2 = gin_b2 + (size_t)i * C_DIM;
        const float* aiw = ain_w + (size_t)i * 3 * C_DIM * C_DIM;
        const float* aib = ain_b + (size_t)i * 3 * C_DIM;
        const float* aow = aout_w + (size_t)i * C_DIM * C_DIM;
        const float* aob = aout_b + (size_t)i * C_DIM;
        const float* mw1 = mlp_w1 + (size_t)i * 2 * C_DIM * C_DIM;
        const float* mb1 = mlp_b1 + (size_t)i * 2 * C_DIM;
        const float* mw2 = mlp_w2 + (size_t)i * 2 * C_DIM * C_DIM;
        const float* mb2 = mlp_b2 + (size_t)i * C_DIM;

        hipMemsetAsync(agg, 0, (size_t)NC * sizeof(float), stream);
        scatter_add<<<E_EDGES * 32 / 256, 256, 0, stream>>>(xin, ei, agg);
        gemm_f32<128><<<dim3(2, 64), 256, 0, stream>>>(xin, agg, gw1, gb1, nullptr, t1, 128, 1);
        gemm_f32<128><<<dim3(2, 64), 256, 0, stream>>>(t1, nullptr, gw2, gb2, xin, g1, 128, 0);
        gemm_f32<128><<<dim3(6, 64), 256, 0, stream>>>(xin, nullptr, aiw, aib, nullptr, qkv, 384, 0);
        attn_kernel<<<dim3(64, 4), 256, 0, stream>>>(qkv, attn_o);
        gemm_f32<128><<<dim3(2, 64), 256, 0, stream>>>(attn_o, nullptr, aow, aob, xin, a2, 128, 0);
        bn_stats<<<32, 256, 0, stream>>>(g1, n1_g + (size_t)i * C_DIM, n1_b + (size_t)i * C_DIM, ss);
        bn_stats<<<32, 256, 0, stream>>>(a2, n2_g + (size_t)i * C_DIM, n2_b + (size_t)i * C_DIM, ss + 256);
        combine2<<<512, 256, 0, stream>>>(g1, a2, ss, ss + 256, hbuf);
        gemm_f32<128><<<dim3(4, 64), 256, 0, stream>>>(hbuf, nullptr, mw1, mb1, nullptr, t2, 256, 1);
        gemm_f32<256><<<dim3(2, 64), 256, 0, stream>>>(t2, nullptr, mw2, mb2, hbuf, m3, 128, 0);
        bn_stats<<<32, 256, 0, stream>>>(m3, n3_g + (size_t)i * C_DIM, n3_b + (size_t)i * C_DIM, ss + 512);
        bn_apply<<<512, 256, 0, stream>>>(m3, ss + 512, xout);
    }

    const float* xf = xB;  // after layer 3 (i=3, odd -> xB)
    gemm_f32<128><<<dim3(1, 64), 256, 0, stream>>>(xf, nullptr, h_w1, h_b1, nullptr, hh1, 64, 1);
    head23<<<16, 256, 0, stream>>>(hh1, h_w2, h_b2, h_w3, h_b3, (float*)d_out);
}

// Round 2
// 968.983 us; speedup vs baseline: 1.8728x; 1.8728x over previous
//
#include <hip/hip_runtime.h>

#define N_NODES 4096
#define C_DIM   128
#define L_LAYERS 4
#define E_EDGES 131072
#define H_HEADS 4
#define D_HEAD  32
#define NC      (N_NODES * C_DIM)

typedef short bf16x8 __attribute__((ext_vector_type(8)));
typedef float f32x4  __attribute__((ext_vector_type(4)));

__device__ __forceinline__ unsigned short f2bf(float f) {
    unsigned int u = __float_as_uint(f);
    u += 0x7fffu + ((u >> 16) & 1u);
    return (unsigned short)(u >> 16);
}

__device__ __forceinline__ bf16x8 pack8(const float* v) {
    bf16x8 o;
#pragma unroll
    for (int i = 0; i < 8; ++i) o[i] = (short)f2bf(v[i]);
    return o;
}

// ---------------------------------------------------------------------------
// CSR build (once per launch): deg histogram -> block scan -> fill
// ---------------------------------------------------------------------------
__global__ __launch_bounds__(256) void hist_kernel(const int* __restrict__ ei,
                                                   int* __restrict__ deg) {
    int e = blockIdx.x * 256 + threadIdx.x;
    atomicAdd(&deg[ei[E_EDGES + e]], 1);
}

__global__ __launch_bounds__(256) void scan_kernel(const int* __restrict__ deg,
                                                   int* __restrict__ rowstart,
                                                   int* __restrict__ cursor) {
    __shared__ int ts[256];
    const int tid = threadIdx.x;
    int loc[16];
    int s = 0;
#pragma unroll
    for (int i = 0; i < 16; ++i) { loc[i] = s; s += deg[tid * 16 + i]; }
    ts[tid] = s;
    __syncthreads();
    for (int off = 1; off < 256; off <<= 1) {
        int t = (tid >= off) ? ts[tid - off] : 0;
        __syncthreads();
        if (tid >= off) ts[tid] += t;
        __syncthreads();
    }
    int off0 = ts[tid] - s;   // exclusive prefix of this thread's chunk
#pragma unroll
    for (int i = 0; i < 16; ++i) {
        int v = off0 + loc[i];
        rowstart[tid * 16 + i] = v;
        cursor[tid * 16 + i] = v;
    }
    if (tid == 255) rowstart[4096] = off0 + s;
}

__global__ __launch_bounds__(256) void fill_kernel(const int* __restrict__ ei,
                                                   int* __restrict__ cursor,
                                                   int* __restrict__ csr_src) {
    int e = blockIdx.x * 256 + threadIdx.x;
    int d = ei[E_EDGES + e];
    int s = ei[e];
    int p = atomicAdd(&cursor[d], 1);
    csr_src[p] = s;
}

// ---------------------------------------------------------------------------
// GIN aggregation as CSR gather: agg[n] = sum_{e in row(n)} x[csr_src[e]]
// one wave per node (4 waves/block), lane owns 2 channels (float2)
// ---------------------------------------------------------------------------
__global__ __launch_bounds__(256) void gather_agg(const float* __restrict__ x,
                                                  const int* __restrict__ rowstart,
                                                  const int* __restrict__ csr_src,
                                                  float* __restrict__ agg) {
    const int node = blockIdx.x * 4 + (threadIdx.x >> 6);
    const int lane = threadIdx.x & 63;
    const int beg = rowstart[node], end = rowstart[node + 1];
    float2 acc0 = {0.f, 0.f}, acc1 = {0.f, 0.f};
    int e = beg;
    for (; e + 4 <= end; e += 4) {
        int s0 = csr_src[e], s1 = csr_src[e + 1], s2 = csr_src[e + 2], s3 = csr_src[e + 3];
        float2 v0 = *(const float2*)(x + (size_t)s0 * C_DIM + lane * 2);
        float2 v1 = *(const float2*)(x + (size_t)s1 * C_DIM + lane * 2);
        float2 v2 = *(const float2*)(x + (size_t)s2 * C_DIM + lane * 2);
        float2 v3 = *(const float2*)(x + (size_t)s3 * C_DIM + lane * 2);
        acc0.x += v0.x + v1.x; acc0.y += v0.y + v1.y;
        acc1.x += v2.x + v3.x; acc1.y += v2.y + v3.y;
    }
    for (; e < end; ++e) {
        int s0 = csr_src[e];
        float2 v0 = *(const float2*)(x + (size_t)s0 * C_DIM + lane * 2);
        acc0.x += v0.x; acc0.y += v0.y;
    }
    float2 o; o.x = acc0.x + acc1.x; o.y = acc0.y + acc1.y;
    *(float2*)(agg + (size_t)node * C_DIM + lane * 2) = o;
}

// ---------------------------------------------------------------------------
// fp32 GEMM: out[n][j] = act( sum_k (A[n][k] (+A2[n][k])) * W[j][k] + bias[j]
//                             (+ resid[n][j]) )
// tile 64 rows x 64 cols, 256 threads, 4x4 micro-tile. grid (J/64, N/64).
// ---------------------------------------------------------------------------
template <int K>
__global__ __launch_bounds__(256) void gemm_f32(const float* __restrict__ A,
                                                const float* __restrict__ A2,
                                                const float* __restrict__ W,
                                                const float* __restrict__ bias,
                                                const float* __restrict__ resid,
                                                float* __restrict__ out,
                                                const int J, const int relu) {
    __shared__ __align__(16) float As[64 * 132];
    __shared__ __align__(16) float Ws[64 * 132];
    const int tid = threadIdx.x;
    const int ct = blockIdx.x, rt = blockIdx.y;
    const int tc = tid & 15, tr = tid >> 4;
    float acc[4][4] = {};

    for (int kc = 0; kc < K; kc += 128) {
        if (kc) __syncthreads();
#pragma unroll
        for (int i = 0; i < 8; ++i) {
            int idx = tid + i * 256;
            int r = idx >> 5, kq = idx & 31;
            float4 av = *(const float4*)(A + (size_t)(rt * 64 + r) * K + kc + kq * 4);
            if (A2) {
                float4 t2 = *(const float4*)(A2 + (size_t)(rt * 64 + r) * K + kc + kq * 4);
                av.x += t2.x; av.y += t2.y; av.z += t2.z; av.w += t2.w;
            }
            *(float4*)(As + r * 132 + kq * 4) = av;
            float4 wv = *(const float4*)(W + (size_t)(ct * 64 + r) * K + kc + kq * 4);
            *(float4*)(Ws + r * 132 + kq * 4) = wv;
        }
        __syncthreads();
#pragma unroll 4
        for (int k4 = 0; k4 < 32; ++k4) {
            float4 a[4], w[4];
#pragma unroll
            for (int i = 0; i < 4; ++i) a[i] = *(const float4*)(As + (tr * 4 + i) * 132 + k4 * 4);
#pragma unroll
            for (int j = 0; j < 4; ++j) w[j] = *(const float4*)(Ws + (tc * 4 + j) * 132 + k4 * 4);
#pragma unroll
            for (int i = 0; i < 4; ++i)
#pragma unroll
                for (int j = 0; j < 4; ++j)
                    acc[i][j] += a[i].x * w[j].x + a[i].y * w[j].y +
                                 a[i].z * w[j].z + a[i].w * w[j].w;
        }
    }

#pragma unroll
    for (int i = 0; i < 4; ++i) {
        int row = rt * 64 + tr * 4 + i;
        float4 o4;
        float* po = (float*)&o4;
#pragma unroll
        for (int j = 0; j < 4; ++j) {
            int col = ct * 64 + tc * 4 + j;
            float v = acc[i][j] + bias[col];
            if (resid) v += resid[(size_t)row * J + col];
            if (relu) v = fmaxf(v, 0.f);
            po[j] = v;
        }
        *(float4*)(out + (size_t)row * J + ct * 64 + tc * 4) = o4;
    }
}

// ---------------------------------------------------------------------------
// Flash attention, bf16 MFMA 16x16x32. grid (N/64, H), 256 threads (4 waves).
// ---------------------------------------------------------------------------
__global__ __launch_bounds__(256) void attn_kernel(const float* __restrict__ qkv,
                                                   float* __restrict__ o_out) {
    __shared__ __align__(16) unsigned short Kl[128 * 32];       // [key][d]
    __shared__ __align__(16) unsigned short Vl[32 * 136];       // [d][key] padded
    __shared__ __align__(16) unsigned short Pl[4 * 16 * 72];    // per-wave [16 q][72]

    const int h   = blockIdx.y;
    const int q0  = blockIdx.x * 64;
    const int tid = threadIdx.x;
    const int wv  = tid >> 6;
    const int lane = tid & 63;
    const int lg  = lane >> 4;
    const int ll  = lane & 15;

    bf16x8 qf;
    {
        const float* qp = qkv + (size_t)(q0 + wv * 16 + ll) * (3 * C_DIM) + h * D_HEAD + lg * 8;
        float tmp[8];
        const float sc = 0.25506973f;  // (1/sqrt(32)) * log2(e)
#pragma unroll
        for (int i = 0; i < 8; ++i) tmp[i] = qp[i] * sc;
        qf = pack8(tmp);
    }

    f32x4 oacc0 = {0.f, 0.f, 0.f, 0.f};
    f32x4 oacc1 = {0.f, 0.f, 0.f, 0.f};
    float m_r[4], l_r[4];
#pragma unroll
    for (int r = 0; r < 4; ++r) { m_r[r] = -1e30f; l_r[r] = 0.f; }

    unsigned short* Pw = Pl + wv * (16 * 72);

    for (int t = 0; t < N_NODES / 128; ++t) {
        __syncthreads();
        {
            const int key = tid >> 1, hf = (tid & 1) * 16;
            const float* kp = qkv + (size_t)(t * 128 + key) * (3 * C_DIM) + C_DIM + h * D_HEAD + hf;
            const float* vp = kp + C_DIM;
            float kb[16];
#pragma unroll
            for (int i = 0; i < 16; ++i) kb[i] = kp[i];
            *(bf16x8*)(Kl + key * 32 + hf)     = pack8(kb);
            *(bf16x8*)(Kl + key * 32 + hf + 8) = pack8(kb + 8);
#pragma unroll
            for (int i = 0; i < 16; ++i) Vl[(hf + i) * 136 + key] = f2bf(vp[i]);
        }
        __syncthreads();

        float s[8][4];
#pragma unroll
        for (int kc = 0; kc < 8; ++kc) {
            bf16x8 kf = *(const bf16x8*)(Kl + (kc * 16 + ll) * 32 + lg * 8);
            f32x4 z = {0.f, 0.f, 0.f, 0.f};
            f32x4 d = __builtin_amdgcn_mfma_f32_16x16x32_bf16(qf, kf, z, 0, 0, 0);
#pragma unroll
            for (int r = 0; r < 4; ++r) s[kc][r] = d[r];
        }

        float alpha[4];
#pragma unroll
        for (int r = 0; r < 4; ++r) {
            float mx = s[0][r];
#pragma unroll
            for (int kc = 1; kc < 8; ++kc) mx = fmaxf(mx, s[kc][r]);
#pragma unroll
            for (int off = 1; off < 16; off <<= 1) mx = fmaxf(mx, __shfl_xor(mx, off, 64));
            float mn = fmaxf(m_r[r], mx);
            alpha[r] = exp2f(m_r[r] - mn);
            m_r[r] = mn;
        }
#pragma unroll
        for (int r = 0; r < 4; ++r) {
            float ls = 0.f;
#pragma unroll
            for (int kc = 0; kc < 8; ++kc) {
                float p = exp2f(s[kc][r] - m_r[r]);
                s[kc][r] = p;
                ls += p;
            }
#pragma unroll
            for (int off = 1; off < 16; off <<= 1) ls += __shfl_xor(ls, off, 64);
            l_r[r] = l_r[r] * alpha[r] + ls;
            oacc0[r] *= alpha[r];
            oacc1[r] *= alpha[r];
        }

#pragma unroll
        for (int kc = 0; kc < 8; ++kc)
#pragma unroll
            for (int r = 0; r < 4; ++r)
                Pw[(lg * 4 + r) * 72 + kc * 16 + ll] = f2bf(s[kc][r]);
        asm volatile("" ::: "memory");

#pragma unroll
        for (int kc2 = 0; kc2 < 4; ++kc2) {
            bf16x8 pf  = *(const bf16x8*)(Pw + ll * 72 + kc2 * 32 + lg * 8);
            bf16x8 vf0 = *(const bf16x8*)(Vl + (ll)      * 136 + kc2 * 32 + lg * 8);
            bf16x8 vf1 = *(const bf16x8*)(Vl + (16 + ll) * 136 + kc2 * 32 + lg * 8);
            oacc0 = __builtin_amdgcn_mfma_f32_16x16x32_bf16(pf, vf0, oacc0, 0, 0, 0);
            oacc1 = __builtin_amdgcn_mfma_f32_16x16x32_bf16(pf, vf1, oacc1, 0, 0, 0);
        }
    }

#pragma unroll
    for (int r = 0; r < 4; ++r) {
        int n = q0 + wv * 16 + lg * 4 + r;
        float inv = 1.f / l_r[r];
        o_out[(size_t)n * C_DIM + h * D_HEAD + ll]      = oacc0[r] * inv;
        o_out[(size_t)n * C_DIM + h * D_HEAD + 16 + ll] = oacc1[r] * inv;
    }
}

// ---------------------------------------------------------------------------
__global__ __launch_bounds__(256) void bn_stats(const float* __restrict__ in,
                                                const float* __restrict__ g,
                                                const float* __restrict__ b,
                                                float* __restrict__ ss) {
    const int c4 = blockIdx.x;
    const int tid = threadIdx.x;
    float s[4] = {0.f, 0.f, 0.f, 0.f}, s2[4] = {0.f, 0.f, 0.f, 0.f};
    for (int r = tid; r < N_NODES; r += 256) {
        float4 v = *(const float4*)(in + (size_t)r * C_DIM + c4 * 4);
        s[0] += v.x; s2[0] += v.x * v.x;
        s[1] += v.y; s2[1] += v.y * v.y;
        s[2] += v.z; s2[2] += v.z * v.z;
        s[3] += v.w; s2[3] += v.w * v.w;
    }
#pragma unroll
    for (int off = 1; off < 64; off <<= 1) {
#pragma unroll
        for (int c = 0; c < 4; ++c) {
            s[c]  += __shfl_xor(s[c],  off, 64);
            s2[c] += __shfl_xor(s2[c], off, 64);
        }
    }
    __shared__ float red[4][8];
    int w = tid >> 6;
    if ((tid & 63) == 0) {
#pragma unroll
        for (int c = 0; c < 4; ++c) { red[w][c] = s[c]; red[w][4 + c] = s2[c]; }
    }
    __syncthreads();
    if (tid == 0) {
#pragma unroll
        for (int c = 0; c < 4; ++c) {
            float fs = red[0][c] + red[1][c] + red[2][c] + red[3][c];
            float fs2 = red[0][4 + c] + red[1][4 + c] + red[2][4 + c] + red[3][4 + c];
            int ch = c4 * 4 + c;
            float mean = fs / N_NODES;
            float var = fs2 / N_NODES - mean * mean;
            float rstd = rsqrtf(var + 1e-5f);
            float scale = g[ch] * rstd;
            ss[ch] = scale;
            ss[C_DIM + ch] = b[ch] - mean * scale;
        }
    }
}

__global__ __launch_bounds__(256) void combine2(const float* __restrict__ p1,
                                                const float* __restrict__ p2,
                                                const float* __restrict__ ss1,
                                                const float* __restrict__ ss2,
                                                float* __restrict__ out) {
    int idx = blockIdx.x * 256 + threadIdx.x;
    int c4 = (idx & 31) * 4;
    float4 v1 = ((const float4*)p1)[idx];
    float4 v2 = ((const float4*)p2)[idx];
    float4 sc1 = *(const float4*)(ss1 + c4), sh1 = *(const float4*)(ss1 + C_DIM + c4);
    float4 sc2 = *(const float4*)(ss2 + c4), sh2 = *(const float4*)(ss2 + C_DIM + c4);
    float4 o;
    o.x = v1.x * sc1.x + sh1.x + v2.x * sc2.x + sh2.x;
    o.y = v1.y * sc1.y + sh1.y + v2.y * sc2.y + sh2.y;
    o.z = v1.z * sc1.z + sh1.z + v2.z * sc2.z + sh2.z;
    o.w = v1.w * sc1.w + sh1.w + v2.w * sc2.w + sh2.w;
    ((float4*)out)[idx] = o;
}

__global__ __launch_bounds__(256) void bn_apply(const float* __restrict__ p,
                                                const float* __restrict__ ss,
                                                float* __restrict__ out) {
    int idx = blockIdx.x * 256 + threadIdx.x;
    int c4 = (idx & 31) * 4;
    float4 v = ((const float4*)p)[idx];
    float4 sc = *(const float4*)(ss + c4), sh = *(const float4*)(ss + C_DIM + c4);
    float4 o;
    o.x = v.x * sc.x + sh.x;
    o.y = v.y * sc.y + sh.y;
    o.z = v.z * sc.z + sh.z;
    o.w = v.w * sc.w + sh.w;
    ((float4*)out)[idx] = o;
}

__global__ __launch_bounds__(256) void head23(const float* __restrict__ hh1,
                                              const float* __restrict__ w2,
                                              const float* __restrict__ b2,
                                              const float* __restrict__ w3,
                                              const float* __restrict__ b3,
                                              float* __restrict__ out) {
    int n = blockIdx.x * 256 + threadIdx.x;
    float4 r[16];
#pragma unroll
    for (int q = 0; q < 16; ++q) r[q] = *(const float4*)(hh1 + (size_t)n * 64 + q * 4);
    float acc = b3[0];
#pragma unroll 4
    for (int j = 0; j < 32; ++j) {
        float sv = b2[j];
#pragma unroll
        for (int q = 0; q < 16; ++q) {
            float4 wr = *(const float4*)(w2 + j * 64 + q * 4);
            sv += r[q].x * wr.x + r[q].y * wr.y + r[q].z * wr.z + r[q].w * wr.w;
        }
        acc += fmaxf(sv, 0.f) * w3[j];
    }
    out[n] = acc;
}

// ---------------------------------------------------------------------------
extern "C" void kernel_launch(void* const* d_in, const int* in_sizes, int n_in,
                              void* d_out, int out_size, void* d_ws, size_t ws_size,
                              hipStream_t stream) {
    (void)in_sizes; (void)n_in; (void)out_size; (void)ws_size;
    const float* x_in   = (const float*)d_in[0];
    const int*   ei     = (const int*)d_in[1];
    const float* gin_w1 = (const float*)d_in[2];
    const float* gin_b1 = (const float*)d_in[3];
    const float* gin_w2 = (const float*)d_in[4];
    const float* gin_b2 = (const float*)d_in[5];
    const float* ain_w  = (const float*)d_in[6];
    const float* ain_b  = (const float*)d_in[7];
    const float* aout_w = (const float*)d_in[8];
    const float* aout_b = (const float*)d_in[9];
    const float* n1_g   = (const float*)d_in[10];
    const float* n1_b   = (const float*)d_in[11];
    const float* n2_g   = (const float*)d_in[12];
    const float* n2_b   = (const float*)d_in[13];
    const float* n3_g   = (const float*)d_in[14];
    const float* n3_b   = (const float*)d_in[15];
    const float* mlp_w1 = (const float*)d_in[16];
    const float* mlp_b1 = (const float*)d_in[17];
    const float* mlp_w2 = (const float*)d_in[18];
    const float* mlp_b2 = (const float*)d_in[19];
    const float* h_w1   = (const float*)d_in[20];
    const float* h_b1   = (const float*)d_in[21];
    const float* h_w2   = (const float*)d_in[22];
    const float* h_b2   = (const float*)d_in[23];
    const float* h_w3   = (const float*)d_in[24];
    const float* h_b3   = (const float*)d_in[25];

    float* f = (float*)d_ws;
    float* agg    = f;                       // chunk 0 (also attn_o)
    float* t1     = f + 1 * (size_t)NC;      // chunk 1 (t2 spans chunks 1-2)
    float* g1     = f + 2 * (size_t)NC;      // chunk 2
    float* t2     = t1;
    float* qkv    = f + 3 * (size_t)NC;      // chunks 3-5
    float* a2     = f + 3 * (size_t)NC;      // chunk 3 (qkv dead by then)
    float* hbuf   = f + 4 * (size_t)NC;      // chunk 4
    float* m3     = f + 5 * (size_t)NC;      // chunk 5
    float* xA     = f + 6 * (size_t)NC;      // chunk 6
    float* xB     = f + 7 * (size_t)NC;      // chunk 7
    float* hh1    = f + 8 * (size_t)NC;      // N*64
    float* ss     = f + 8 * (size_t)NC + (size_t)N_NODES * 64;  // 3*256 floats
    float* attn_o = agg;

    // CSR arrays (ints) after all float buffers
    int* ibase    = (int*)(ss + 768);
    int* deg      = ibase;                  // 4096
    int* rowstart = ibase + 4096;           // 4098 (pad)
    int* cursor   = ibase + 4096 + 4098;    // 4096
    int* csr_src  = ibase + 4096 + 4098 + 4096;  // 131072

    // build CSR once (edge_index constant within the call)
    hipMemsetAsync(deg, 0, 4096 * sizeof(int), stream);
    hist_kernel<<<E_EDGES / 256, 256, 0, stream>>>(ei, deg);
    scan_kernel<<<1, 256, 0, stream>>>(deg, rowstart, cursor);
    fill_kernel<<<E_EDGES / 256, 256, 0, stream>>>(ei, cursor, csr_src);

    for (int i = 0; i < L_LAYERS; ++i) {
        const float* xin = (i == 0) ? x_in : ((i & 1) ? xA : xB);
        float* xout = (i & 1) ? xB : xA;
        const float* gw1 = gin_w1 + (size_t)i * C_DIM * C_DIM;
        const float* gb1 = gin_b1 + (size_t)i * C_DIM;
        const float* gw2 = gin_w2 + (size_t)i * C_DIM * C_DIM;
        const float* gb2 = gin_b2 + (size_t)i * C_DIM;
        const float* aiw = ain_w + (size_t)i * 3 * C_DIM * C_DIM;
        const float* aib = ain_b + (size_t)i * 3 * C_DIM;
        const float* aow = aout_w + (size_t)i * C_DIM * C_DIM;
        const float* aob = aout_b + (size_t)i * C_DIM;
        const float* mw1 = mlp_w1 + (size_t)i * 2 * C_DIM * C_DIM;
        const float* mb1 = mlp_b1 + (size_t)i * 2 * C_DIM;
        const float* mw2 = mlp_w2 + (size_t)i * 2 * C_DIM * C_DIM;
        const float* mb2 = mlp_b2 + (size_t)i * C_DIM;

        gather_agg<<<N_NODES / 4, 256, 0, stream>>>(xin, rowstart, csr_src, agg);
        gemm_f32<128><<<dim3(2, 64), 256, 0, stream>>>(xin, agg, gw1, gb1, nullptr, t1, 128, 1);
        gemm_f32<128><<<dim3(2, 64), 256, 0, stream>>>(t1, nullptr, gw2, gb2, xin, g1, 128, 0);
        gemm_f32<128><<<dim3(6, 64), 256, 0, stream>>>(xin, nullptr, aiw, aib, nullptr, qkv, 384, 0);
        attn_kernel<<<dim3(64, 4), 256, 0, stream>>>(qkv, attn_o);
        gemm_f32<128><<<dim3(2, 64), 256, 0, stream>>>(attn_o, nullptr, aow, aob, xin, a2, 128, 0);
        bn_stats<<<32, 256, 0, stream>>>(g1, n1_g + (size_t)i * C_DIM, n1_b + (size_t)i * C_DIM, ss);
        bn_stats<<<32, 256, 0, stream>>>(a2, n2_g + (size_t)i * C_DIM, n2_b + (size_t)i * C_DIM, ss + 256);
        combine2<<<512, 256, 0, stream>>>(g1, a2, ss, ss + 256, hbuf);
        gemm_f32<128><<<dim3(4, 64), 256, 0, stream>>>(hbuf, nullptr, mw1, mb1, nullptr, t2, 256, 1);
        gemm_f32<256><<<dim3(2, 64), 256, 0, stream>>>(t2, nullptr, mw2, mb2, hbuf, m3, 128, 0);
        bn_stats<<<32, 256, 0, stream>>>(m3, n3_g + (size_t)i * C_DIM, n3_b + (size_t)i * C_DIM, ss + 512);
        bn_apply<<<512, 256, 0, stream>>>(m3, ss + 512, xout);
    }

    const float* xf = xB;  // after layer 3 (i=3, odd -> xB)
    gemm_f32<128><<<dim3(1, 64), 256, 0, stream>>>(xf, nullptr, h_w1, h_b1, nullptr, hh1, 64, 1);
    head23<<<16, 256, 0, stream>>>(hh1, h_w2, h_b2, h_w3, h_b3, (float*)d_out);
}

// Round 4
// 856.977 us; speedup vs baseline: 2.1176x; 1.1307x over previous
//
#include <hip/hip_runtime.h>

#define N_NODES 4096
#define C_DIM   128
#define L_LAYERS 4
#define E_EDGES 131072
#define H_HEADS 4
#define D_HEAD  32
#define NC      (N_NODES * C_DIM)
#define P_STRIDE 136   // >=128 keys; multiple of 8 ushorts (16B-aligned bf16x8 reads)

typedef short bf16x8 __attribute__((ext_vector_type(8)));
typedef float f32x4  __attribute__((ext_vector_type(4)));

__device__ __forceinline__ unsigned short f2bf(float f) {
    unsigned int u = __float_as_uint(f);
    u += 0x7fffu + ((u >> 16) & 1u);
    return (unsigned short)(u >> 16);
}

// ---------------------------------------------------------------------------
// CSR build (once per launch): deg histogram -> block scan -> fill
// ---------------------------------------------------------------------------
__global__ __launch_bounds__(256) void hist_kernel(const int* __restrict__ ei,
                                                   int* __restrict__ deg) {
    int e = blockIdx.x * 256 + threadIdx.x;
    atomicAdd(&deg[ei[E_EDGES + e]], 1);
}

__global__ __launch_bounds__(256) void scan_kernel(const int* __restrict__ deg,
                                                   int* __restrict__ rowstart,
                                                   int* __restrict__ cursor) {
    __shared__ int ts[256];
    const int tid = threadIdx.x;
    int loc[16];
    int s = 0;
#pragma unroll
    for (int i = 0; i < 16; ++i) { loc[i] = s; s += deg[tid * 16 + i]; }
    ts[tid] = s;
    __syncthreads();
    for (int off = 1; off < 256; off <<= 1) {
        int t = (tid >= off) ? ts[tid - off] : 0;
        __syncthreads();
        if (tid >= off) ts[tid] += t;
        __syncthreads();
    }
    int off0 = ts[tid] - s;
#pragma unroll
    for (int i = 0; i < 16; ++i) {
        int v = off0 + loc[i];
        rowstart[tid * 16 + i] = v;
        cursor[tid * 16 + i] = v;
    }
    if (tid == 255) rowstart[4096] = off0 + s;
}

__global__ __launch_bounds__(256) void fill_kernel(const int* __restrict__ ei,
                                                   int* __restrict__ cursor,
                                                   int* __restrict__ csr_src) {
    int e = blockIdx.x * 256 + threadIdx.x;
    int d = ei[E_EDGES + e];
    int s = ei[e];
    int p = atomicAdd(&cursor[d], 1);
    csr_src[p] = s;
}

// ---------------------------------------------------------------------------
// GIN aggregation as CSR gather
// ---------------------------------------------------------------------------
__global__ __launch_bounds__(256) void gather_agg(const float* __restrict__ x,
                                                  const int* __restrict__ rowstart,
                                                  const int* __restrict__ csr_src,
                                                  float* __restrict__ agg) {
    const int node = blockIdx.x * 4 + (threadIdx.x >> 6);
    const int lane = threadIdx.x & 63;
    const int beg = rowstart[node], end = rowstart[node + 1];
    float2 acc0 = {0.f, 0.f}, acc1 = {0.f, 0.f};
    int e = beg;
    for (; e + 4 <= end; e += 4) {
        int s0 = csr_src[e], s1 = csr_src[e + 1], s2 = csr_src[e + 2], s3 = csr_src[e + 3];
        float2 v0 = *(const float2*)(x + (size_t)s0 * C_DIM + lane * 2);
        float2 v1 = *(const float2*)(x + (size_t)s1 * C_DIM + lane * 2);
        float2 v2 = *(const float2*)(x + (size_t)s2 * C_DIM + lane * 2);
        float2 v3 = *(const float2*)(x + (size_t)s3 * C_DIM + lane * 2);
        acc0.x += v0.x + v1.x; acc0.y += v0.y + v1.y;
        acc1.x += v2.x + v3.x; acc1.y += v2.y + v3.y;
    }
    for (; e < end; ++e) {
        int s0 = csr_src[e];
        float2 v0 = *(const float2*)(x + (size_t)s0 * C_DIM + lane * 2);
        acc0.x += v0.x; acc0.y += v0.y;
    }
    float2 o; o.x = acc0.x + acc1.x; o.y = acc0.y + acc1.y;
    *(float2*)(agg + (size_t)node * C_DIM + lane * 2) = o;
}

// ---------------------------------------------------------------------------
// fp32 GEMM (f32 output path)
// ---------------------------------------------------------------------------
template <int K>
__global__ __launch_bounds__(256) void gemm_f32(const float* __restrict__ A,
                                                const float* __restrict__ A2,
                                                const float* __restrict__ W,
                                                const float* __restrict__ bias,
                                                const float* __restrict__ resid,
                                                float* __restrict__ out,
                                                const int J, const int relu) {
    __shared__ __align__(16) float As[64 * 132];
    __shared__ __align__(16) float Ws[64 * 132];
    const int tid = threadIdx.x;
    const int ct = blockIdx.x, rt = blockIdx.y;
    const int tc = tid & 15, tr = tid >> 4;
    float acc[4][4] = {};

    for (int kc = 0; kc < K; kc += 128) {
        if (kc) __syncthreads();
#pragma unroll
        for (int i = 0; i < 8; ++i) {
            int idx = tid + i * 256;
            int r = idx >> 5, kq = idx & 31;
            float4 av = *(const float4*)(A + (size_t)(rt * 64 + r) * K + kc + kq * 4);
            if (A2) {
                float4 t2 = *(const float4*)(A2 + (size_t)(rt * 64 + r) * K + kc + kq * 4);
                av.x += t2.x; av.y += t2.y; av.z += t2.z; av.w += t2.w;
            }
            *(float4*)(As + r * 132 + kq * 4) = av;
            float4 wv = *(const float4*)(W + (size_t)(ct * 64 + r) * K + kc + kq * 4);
            *(float4*)(Ws + r * 132 + kq * 4) = wv;
        }
        __syncthreads();
#pragma unroll 4
        for (int k4 = 0; k4 < 32; ++k4) {
            float4 a[4], w[4];
#pragma unroll
            for (int i = 0; i < 4; ++i) a[i] = *(const float4*)(As + (tr * 4 + i) * 132 + k4 * 4);
#pragma unroll
            for (int j = 0; j < 4; ++j) w[j] = *(const float4*)(Ws + (tc * 4 + j) * 132 + k4 * 4);
#pragma unroll
            for (int i = 0; i < 4; ++i)
#pragma unroll
                for (int j = 0; j < 4; ++j)
                    acc[i][j] += a[i].x * w[j].x + a[i].y * w[j].y +
                                 a[i].z * w[j].z + a[i].w * w[j].w;
        }
    }

#pragma unroll
    for (int i = 0; i < 4; ++i) {
        int row = rt * 64 + tr * 4 + i;
        float4 o4;
        float* po = (float*)&o4;
#pragma unroll
        for (int j = 0; j < 4; ++j) {
            int col = ct * 64 + tc * 4 + j;
            float v = acc[i][j] + bias[col];
            if (resid) v += resid[(size_t)row * J + col];
            if (relu) v = fmaxf(v, 0.f);
            po[j] = v;
        }
        *(float4*)(out + (size_t)row * J + ct * 64 + tc * 4) = o4;
    }
}

// ---------------------------------------------------------------------------
// QKV GEMM with bf16 epilogue into attention-friendly layouts:
//   Qb [H][N][32] (pre-scaled by 1/sqrt(d)*log2e), Kb [H][N][32], VT [H][32][N]
// ---------------------------------------------------------------------------
__global__ __launch_bounds__(256) void gemm_qkv(const float* __restrict__ A,
                                                const float* __restrict__ W,
                                                const float* __restrict__ bias,
                                                unsigned short* __restrict__ Qb,
                                                unsigned short* __restrict__ Kb,
                                                unsigned short* __restrict__ VT) {
    __shared__ __align__(16) float As[64 * 132];
    __shared__ __align__(16) float Ws[64 * 132];
    const int tid = threadIdx.x;
    const int ct = blockIdx.x, rt = blockIdx.y;
    const int tc = tid & 15, tr = tid >> 4;
    float acc[4][4] = {};

#pragma unroll
    for (int i = 0; i < 8; ++i) {
        int idx = tid + i * 256;
        int r = idx >> 5, kq = idx & 31;
        *(float4*)(As + r * 132 + kq * 4) =
            *(const float4*)(A + (size_t)(rt * 64 + r) * 128 + kq * 4);
        *(float4*)(Ws + r * 132 + kq * 4) =
            *(const float4*)(W + (size_t)(ct * 64 + r) * 128 + kq * 4);
    }
    __syncthreads();
#pragma unroll 4
    for (int k4 = 0; k4 < 32; ++k4) {
        float4 a[4], w[4];
#pragma unroll
        for (int i = 0; i < 4; ++i) a[i] = *(const float4*)(As + (tr * 4 + i) * 132 + k4 * 4);
#pragma unroll
        for (int j = 0; j < 4; ++j) w[j] = *(const float4*)(Ws + (tc * 4 + j) * 132 + k4 * 4);
#pragma unroll
        for (int i = 0; i < 4; ++i)
#pragma unroll
            for (int j = 0; j < 4; ++j)
                acc[i][j] += a[i].x * w[j].x + a[i].y * w[j].y +
                             a[i].z * w[j].z + a[i].w * w[j].w;
    }

    const float qsc = 0.25506973f;  // (1/sqrt(32)) * log2(e)
#pragma unroll
    for (int i = 0; i < 4; ++i) {
        int row = rt * 64 + tr * 4 + i;
#pragma unroll
        for (int j = 0; j < 4; ++j) {
            int col = ct * 64 + tc * 4 + j;
            float v = acc[i][j] + bias[col];
            if (col < 128) {
                int hh = col >> 5, d = col & 31;
                Qb[((size_t)hh * N_NODES + row) * D_HEAD + d] = f2bf(v * qsc);
            } else if (col < 256) {
                int c2 = col - 128, hh = c2 >> 5, d = c2 & 31;
                Kb[((size_t)hh * N_NODES + row) * D_HEAD + d] = f2bf(v);
            } else {
                int c2 = col - 256, hh = c2 >> 5, d = c2 & 31;
                VT[((size_t)hh * D_HEAD + d) * N_NODES + row] = f2bf(v);
            }
        }
    }
}

// ---------------------------------------------------------------------------
// Flash attention: grid (N/16, H), 256 threads = 4 waves.
// All 4 waves share the same 16 q-rows; each wave owns a 1024-key range.
// K/V fragments read directly from global (L2-resident bf16). P goes through
// wave-private LDS with stride P_STRIDE=136 (>=128 keys -> no row clobber,
// no cross-wave spill: this was R3's fatal OOB bug with stride 72).
// ---------------------------------------------------------------------------
__global__ __launch_bounds__(256) void attn_kernel(const unsigned short* __restrict__ Qb,
                                                   const unsigned short* __restrict__ Kb,
                                                   const unsigned short* __restrict__ VT,
                                                   float* __restrict__ o_out) {
    __shared__ __align__(16) unsigned short Pl[4 * 16 * P_STRIDE];
    __shared__ __align__(16) float Ouns[4][16][33];
    __shared__ float Ml[4][16], Ll[4][16];

    const int h   = blockIdx.y;
    const int q0  = blockIdx.x * 16;
    const int tid = threadIdx.x;
    const int wv  = tid >> 6;
    const int lane = tid & 63;
    const int lg  = lane >> 4;
    const int ll  = lane & 15;

    const unsigned short* Qh = Qb + ((size_t)h * N_NODES + q0) * D_HEAD;
    const unsigned short* Kh = Kb + (size_t)h * N_NODES * D_HEAD;
    const unsigned short* Vh = VT + (size_t)h * D_HEAD * N_NODES;

    bf16x8 qf = *(const bf16x8*)(Qh + ll * D_HEAD + lg * 8);

    f32x4 oacc0 = {0.f, 0.f, 0.f, 0.f};
    f32x4 oacc1 = {0.f, 0.f, 0.f, 0.f};
    float m_r[4], l_r[4];
#pragma unroll
    for (int r = 0; r < 4; ++r) { m_r[r] = -1e30f; l_r[r] = 0.f; }

    unsigned short* Pw = Pl + wv * (16 * P_STRIDE);
    const int k0 = wv * (N_NODES / 4);

    for (int t = 0; t < (N_NODES / 4) / 128; ++t) {
        const int kt = k0 + t * 128;

        // prefetch V fragments (consumed after softmax -> latency hidden)
        bf16x8 vf[8];
#pragma unroll
        for (int kc2 = 0; kc2 < 4; ++kc2) {
            vf[kc2 * 2]     = *(const bf16x8*)(Vh + (size_t)ll * N_NODES + kt + kc2 * 32 + lg * 8);
            vf[kc2 * 2 + 1] = *(const bf16x8*)(Vh + (size_t)(16 + ll) * N_NODES + kt + kc2 * 32 + lg * 8);
        }

        // S = Q K^T (K frags straight from global, coalesced per wave)
        float s[8][4];
#pragma unroll
        for (int kc = 0; kc < 8; ++kc) {
            bf16x8 kf = *(const bf16x8*)(Kh + (size_t)(kt + kc * 16 + ll) * D_HEAD + lg * 8);
            f32x4 z = {0.f, 0.f, 0.f, 0.f};
            f32x4 d = __builtin_amdgcn_mfma_f32_16x16x32_bf16(qf, kf, z, 0, 0, 0);
#pragma unroll
            for (int r = 0; r < 4; ++r) s[kc][r] = d[r];
        }

        // online softmax (rows live in 16-lane groups)
        float alpha[4];
#pragma unroll
        for (int r = 0; r < 4; ++r) {
            float mx = s[0][r];
#pragma unroll
            for (int kc = 1; kc < 8; ++kc) mx = fmaxf(mx, s[kc][r]);
#pragma unroll
            for (int off = 1; off < 16; off <<= 1) mx = fmaxf(mx, __shfl_xor(mx, off, 64));
            float mn = fmaxf(m_r[r], mx);
            alpha[r] = exp2f(m_r[r] - mn);
            m_r[r] = mn;
        }
#pragma unroll
        for (int r = 0; r < 4; ++r) {
            float ls = 0.f;
#pragma unroll
            for (int kc = 0; kc < 8; ++kc) {
                float p = exp2f(s[kc][r] - m_r[r]);
                s[kc][r] = p;
                ls += p;
            }
#pragma unroll
            for (int off = 1; off < 16; off <<= 1) ls += __shfl_xor(ls, off, 64);
            l_r[r] = l_r[r] * alpha[r] + ls;
            oacc0[r] *= alpha[r];
            oacc1[r] *= alpha[r];
        }

        // P -> wave-private LDS (bf16), then PV
#pragma unroll
        for (int kc = 0; kc < 8; ++kc)
#pragma unroll
            for (int r = 0; r < 4; ++r)
                Pw[(lg * 4 + r) * P_STRIDE + kc * 16 + ll] = f2bf(s[kc][r]);
        asm volatile("" ::: "memory");

#pragma unroll
        for (int kc2 = 0; kc2 < 4; ++kc2) {
            bf16x8 pf = *(const bf16x8*)(Pw + ll * P_STRIDE + kc2 * 32 + lg * 8);
            oacc0 = __builtin_amdgcn_mfma_f32_16x16x32_bf16(pf, vf[kc2 * 2],     oacc0, 0, 0, 0);
            oacc1 = __builtin_amdgcn_mfma_f32_16x16x32_bf16(pf, vf[kc2 * 2 + 1], oacc1, 0, 0, 0);
        }
    }

    // publish per-wave partials
#pragma unroll
    for (int r = 0; r < 4; ++r) {
        Ouns[wv][lg * 4 + r][ll]      = oacc0[r];
        Ouns[wv][lg * 4 + r][16 + ll] = oacc1[r];
    }
    if (ll == 0) {
#pragma unroll
        for (int r = 0; r < 4; ++r) { Ml[wv][lg * 4 + r] = m_r[r]; Ll[wv][lg * 4 + r] = l_r[r]; }
    }
    __syncthreads();

    // merge 4 key-split partials: thread -> (row = tid>>4, col = tid&15, col+16)
    {
        const int row = tid >> 4, col = tid & 15;
        float M = Ml[0][row];
#pragma unroll
        for (int w = 1; w < 4; ++w) M = fmaxf(M, Ml[w][row]);
        float e[4], Lsum = 0.f;
#pragma unroll
        for (int w = 0; w < 4; ++w) { e[w] = exp2f(Ml[w][row] - M); Lsum += Ll[w][row] * e[w]; }
        float inv = 1.f / Lsum;
        float o0 = 0.f, o1 = 0.f;
#pragma unroll
        for (int w = 0; w < 4; ++w) {
            o0 += Ouns[w][row][col] * e[w];
            o1 += Ouns[w][row][16 + col] * e[w];
        }
        o_out[(size_t)(q0 + row) * C_DIM + h * D_HEAD + col]      = o0 * inv;
        o_out[(size_t)(q0 + row) * C_DIM + h * D_HEAD + 16 + col] = o1 * inv;
    }
}

// ---------------------------------------------------------------------------
__global__ __launch_bounds__(256) void bn_stats(const float* __restrict__ in,
                                                const float* __restrict__ g,
                                                const float* __restrict__ b,
                                                float* __restrict__ ss) {
    const int c4 = blockIdx.x;
    const int tid = threadIdx.x;
    float s[4] = {0.f, 0.f, 0.f, 0.f}, s2[4] = {0.f, 0.f, 0.f, 0.f};
    for (int r = tid; r < N_NODES; r += 256) {
        float4 v = *(const float4*)(in + (size_t)r * C_DIM + c4 * 4);
        s[0] += v.x; s2[0] += v.x * v.x;
        s[1] += v.y; s2[1] += v.y * v.y;
        s[2] += v.z; s2[2] += v.z * v.z;
        s[3] += v.w; s2[3] += v.w * v.w;
    }
#pragma unroll
    for (int off = 1; off < 64; off <<= 1) {
#pragma unroll
        for (int c = 0; c < 4; ++c) {
            s[c]  += __shfl_xor(s[c],  off, 64);
            s2[c] += __shfl_xor(s2[c], off, 64);
        }
    }
    __shared__ float red[4][8];
    int w = tid >> 6;
    if ((tid & 63) == 0) {
#pragma unroll
        for (int c = 0; c < 4; ++c) { red[w][c] = s[c]; red[w][4 + c] = s2[c]; }
    }
    __syncthreads();
    if (tid == 0) {
#pragma unroll
        for (int c = 0; c < 4; ++c) {
            float fs = red[0][c] + red[1][c] + red[2][c] + red[3][c];
            float fs2 = red[0][4 + c] + red[1][4 + c] + red[2][4 + c] + red[3][4 + c];
            int ch = c4 * 4 + c;
            float mean = fs / N_NODES;
            float var = fs2 / N_NODES - mean * mean;
            float rstd = rsqrtf(var + 1e-5f);
            float scale = g[ch] * rstd;
            ss[ch] = scale;
            ss[C_DIM + ch] = b[ch] - mean * scale;
        }
    }
}

__global__ __launch_bounds__(256) void combine2(const float* __restrict__ p1,
                                                const float* __restrict__ p2,
                                                const float* __restrict__ ss1,
                                                const float* __restrict__ ss2,
                                                float* __restrict__ out) {
    int idx = blockIdx.x * 256 + threadIdx.x;
    int c4 = (idx & 31) * 4;
    float4 v1 = ((const float4*)p1)[idx];
    float4 v2 = ((const float4*)p2)[idx];
    float4 sc1 = *(const float4*)(ss1 + c4), sh1 = *(const float4*)(ss1 + C_DIM + c4);
    float4 sc2 = *(const float4*)(ss2 + c4), sh2 = *(const float4*)(ss2 + C_DIM + c4);
    float4 o;
    o.x = v1.x * sc1.x + sh1.x + v2.x * sc2.x + sh2.x;
    o.y = v1.y * sc1.y + sh1.y + v2.y * sc2.y + sh2.y;
    o.z = v1.z * sc1.z + sh1.z + v2.z * sc2.z + sh2.z;
    o.w = v1.w * sc1.w + sh1.w + v2.w * sc2.w + sh2.w;
    ((float4*)out)[idx] = o;
}

__global__ __launch_bounds__(256) void bn_apply(const float* __restrict__ p,
                                                const float* __restrict__ ss,
                                                float* __restrict__ out) {
    int idx = blockIdx.x * 256 + threadIdx.x;
    int c4 = (idx & 31) * 4;
    float4 v = ((const float4*)p)[idx];
    float4 sc = *(const float4*)(ss + c4), sh = *(const float4*)(ss + C_DIM + c4);
    float4 o;
    o.x = v.x * sc.x + sh.x;
    o.y = v.y * sc.y + sh.y;
    o.z = v.z * sc.z + sh.z;
    o.w = v.w * sc.w + sh.w;
    ((float4*)out)[idx] = o;
}

__global__ __launch_bounds__(256) void head23(const float* __restrict__ hh1,
                                              const float* __restrict__ w2,
                                              const float* __restrict__ b2,
                                              const float* __restrict__ w3,
                                              const float* __restrict__ b3,
                                              float* __restrict__ out) {
    int n = blockIdx.x * 256 + threadIdx.x;
    float4 r[16];
#pragma unroll
    for (int q = 0; q < 16; ++q) r[q] = *(const float4*)(hh1 + (size_t)n * 64 + q * 4);
    float acc = b3[0];
#pragma unroll 4
    for (int j = 0; j < 32; ++j) {
        float sv = b2[j];
#pragma unroll
        for (int q = 0; q < 16; ++q) {
            float4 wr = *(const float4*)(w2 + j * 64 + q * 4);
            sv += r[q].x * wr.x + r[q].y * wr.y + r[q].z * wr.z + r[q].w * wr.w;
        }
        acc += fmaxf(sv, 0.f) * w3[j];
    }
    out[n] = acc;
}

// ---------------------------------------------------------------------------
extern "C" void kernel_launch(void* const* d_in, const int* in_sizes, int n_in,
                              void* d_out, int out_size, void* d_ws, size_t ws_size,
                              hipStream_t stream) {
    (void)in_sizes; (void)n_in; (void)out_size; (void)ws_size;
    const float* x_in   = (const float*)d_in[0];
    const int*   ei     = (const int*)d_in[1];
    const float* gin_w1 = (const float*)d_in[2];
    const float* gin_b1 = (const float*)d_in[3];
    const float* gin_w2 = (const float*)d_in[4];
    const float* gin_b2 = (const float*)d_in[5];
    const float* ain_w  = (const float*)d_in[6];
    const float* ain_b  = (const float*)d_in[7];
    const float* aout_w = (const float*)d_in[8];
    const float* aout_b = (const float*)d_in[9];
    const float* n1_g   = (const float*)d_in[10];
    const float* n1_b   = (const float*)d_in[11];
    const float* n2_g   = (const float*)d_in[12];
    const float* n2_b   = (const float*)d_in[13];
    const float* n3_g   = (const float*)d_in[14];
    const float* n3_b   = (const float*)d_in[15];
    const float* mlp_w1 = (const float*)d_in[16];
    const float* mlp_b1 = (const float*)d_in[17];
    const float* mlp_w2 = (const float*)d_in[18];
    const float* mlp_b2 = (const float*)d_in[19];
    const float* h_w1   = (const float*)d_in[20];
    const float* h_b1   = (const float*)d_in[21];
    const float* h_w2   = (const float*)d_in[22];
    const float* h_b2   = (const float*)d_in[23];
    const float* h_w3   = (const float*)d_in[24];
    const float* h_b3   = (const float*)d_in[25];

    float* f = (float*)d_ws;
    float* agg    = f;                       // chunk 0 (also attn_o)
    float* t1     = f + 1 * (size_t)NC;      // chunk 1 (t2 spans chunks 1-2)
    float* g1     = f + 2 * (size_t)NC;      // chunk 2
    float* t2     = t1;
    // chunks 3-4: bf16 Qb/Kb/VT while attention runs; a2/hbuf after (QKV dead)
    unsigned short* Qb = (unsigned short*)(f + 3 * (size_t)NC);      // 1MB
    unsigned short* Kb = Qb + (size_t)H_HEADS * N_NODES * D_HEAD;    // 1MB
    unsigned short* VT = Kb + (size_t)H_HEADS * N_NODES * D_HEAD;    // 1MB (into chunk 4)
    float* a2     = f + 3 * (size_t)NC;      // chunk 3 (QKV consumed by then)
    float* hbuf   = f + 4 * (size_t)NC;      // chunk 4
    float* m3     = f + 5 * (size_t)NC;      // chunk 5
    float* xA     = f + 6 * (size_t)NC;      // chunk 6
    float* xB     = f + 7 * (size_t)NC;      // chunk 7
    float* hh1    = f + 8 * (size_t)NC;      // N*64
    float* ss     = f + 8 * (size_t)NC + (size_t)N_NODES * 64;  // 3*256 floats
    float* attn_o = agg;

    int* ibase    = (int*)(ss + 768);
    int* deg      = ibase;
    int* rowstart = ibase + 4096;
    int* cursor   = ibase + 4096 + 4098;
    int* csr_src  = ibase + 4096 + 4098 + 4096;

    hipMemsetAsync(deg, 0, 4096 * sizeof(int), stream);
    hist_kernel<<<E_EDGES / 256, 256, 0, stream>>>(ei, deg);
    scan_kernel<<<1, 256, 0, stream>>>(deg, rowstart, cursor);
    fill_kernel<<<E_EDGES / 256, 256, 0, stream>>>(ei, cursor, csr_src);

    for (int i = 0; i < L_LAYERS; ++i) {
        const float* xin = (i == 0) ? x_in : ((i & 1) ? xA : xB);
        float* xout = (i & 1) ? xB : xA;
        const float* gw1 = gin_w1 + (size_t)i * C_DIM * C_DIM;
        const float* gb1 = gin_b1 + (size_t)i * C_DIM;
        const float* gw2 = gin_w2 + (size_t)i * C_DIM * C_DIM;
        const float* gb2 = gin_b2 + (size_t)i * C_DIM;
        const float* aiw = ain_w + (size_t)i * 3 * C_DIM * C_DIM;
        const float* aib = ain_b + (size_t)i * 3 * C_DIM;
        const float* aow = aout_w + (size_t)i * C_DIM * C_DIM;
        const float* aob = aout_b + (size_t)i * C_DIM;
        const float* mw1 = mlp_w1 + (size_t)i * 2 * C_DIM * C_DIM;
        const float* mb1 = mlp_b1 + (size_t)i * 2 * C_DIM;
        const float* mw2 = mlp_w2 + (size_t)i * 2 * C_DIM * C_DIM;
        const float* mb2 = mlp_b2 + (size_t)i * C_DIM;

        gather_agg<<<N_NODES / 4, 256, 0, stream>>>(xin, rowstart, csr_src, agg);
        gemm_f32<128><<<dim3(2, 64), 256, 0, stream>>>(xin, agg, gw1, gb1, nullptr, t1, 128, 1);
        gemm_f32<128><<<dim3(2, 64), 256, 0, stream>>>(t1, nullptr, gw2, gb2, xin, g1, 128, 0);
        gemm_qkv<<<dim3(6, 64), 256, 0, stream>>>(xin, aiw, aib, Qb, Kb, VT);
        attn_kernel<<<dim3(N_NODES / 16, H_HEADS), 256, 0, stream>>>(Qb, Kb, VT, attn_o);
        gemm_f32<128><<<dim3(2, 64), 256, 0, stream>>>(attn_o, nullptr, aow, aob, xin, a2, 128, 0);
        bn_stats<<<32, 256, 0, stream>>>(g1, n1_g + (size_t)i * C_DIM, n1_b + (size_t)i * C_DIM, ss);
        bn_stats<<<32, 256, 0, stream>>>(a2, n2_g + (size_t)i * C_DIM, n2_b + (size_t)i * C_DIM, ss + 256);
        combine2<<<512, 256, 0, stream>>>(g1, a2, ss, ss + 256, hbuf);
        gemm_f32<128><<<dim3(4, 64), 256, 0, stream>>>(hbuf, nullptr, mw1, mb1, nullptr, t2, 256, 1);
        gemm_f32<256><<<dim3(2, 64), 256, 0, stream>>>(t2, nullptr, mw2, mb2, hbuf, m3, 128, 0);
        bn_stats<<<32, 256, 0, stream>>>(m3, n3_g + (size_t)i * C_DIM, n3_b + (size_t)i * C_DIM, ss + 512);
        bn_apply<<<512, 256, 0, stream>>>(m3, ss + 512, xout);
    }

    const float* xf = xB;
    gemm_f32<128><<<dim3(1, 64), 256, 0, stream>>>(xf, nullptr, h_w1, h_b1, nullptr, hh1, 64, 1);
    head23<<<16, 256, 0, stream>>>(hh1, h_w2, h_b2, h_w3, h_b3, (float*)d_out);
}

// Round 5
// 577.998 us; speedup vs baseline: 3.1397x; 1.4827x over previous
//
#include <hip/hip_runtime.h>

#define N_NODES 4096
#define C_DIM   128
#define L_LAYERS 4
#define E_EDGES 131072
#define H_HEADS 4
#define D_HEAD  32
#define NC      (N_NODES * C_DIM)     // floats per [N][C] buffer
#define NCu     (N_NODES * C_DIM)     // ushorts per [N][C] bf16 buffer
#define P_STRIDE 136

typedef short bf16x8 __attribute__((ext_vector_type(8)));
typedef float f32x4  __attribute__((ext_vector_type(4)));

__device__ __forceinline__ unsigned short f2bf(float f) {
    unsigned int u = __float_as_uint(f);
    u += 0x7fffu + ((u >> 16) & 1u);
    return (unsigned short)(u >> 16);
}

__device__ __forceinline__ bf16x8 pack8(const float* v) {
    bf16x8 o;
#pragma unroll
    for (int i = 0; i < 8; ++i) o[i] = (short)f2bf(v[i]);
    return o;
}

// ---------------------------------------------------------------------------
// CSR build (once per launch)
// ---------------------------------------------------------------------------
__global__ __launch_bounds__(256) void hist_kernel(const int* __restrict__ ei,
                                                   int* __restrict__ deg) {
    int e = blockIdx.x * 256 + threadIdx.x;
    atomicAdd(&deg[ei[E_EDGES + e]], 1);
}

__global__ __launch_bounds__(256) void scan_kernel(const int* __restrict__ deg,
                                                   int* __restrict__ rowstart,
                                                   int* __restrict__ cursor) {
    __shared__ int ts[256];
    const int tid = threadIdx.x;
    int loc[16];
    int s = 0;
#pragma unroll
    for (int i = 0; i < 16; ++i) { loc[i] = s; s += deg[tid * 16 + i]; }
    ts[tid] = s;
    __syncthreads();
    for (int off = 1; off < 256; off <<= 1) {
        int t = (tid >= off) ? ts[tid - off] : 0;
        __syncthreads();
        if (tid >= off) ts[tid] += t;
        __syncthreads();
    }
    int off0 = ts[tid] - s;
#pragma unroll
    for (int i = 0; i < 16; ++i) {
        int v = off0 + loc[i];
        rowstart[tid * 16 + i] = v;
        cursor[tid * 16 + i] = v;
    }
    if (tid == 255) rowstart[4096] = off0 + s;
}

__global__ __launch_bounds__(256) void fill_kernel(const int* __restrict__ ei,
                                                   int* __restrict__ cursor,
                                                   int* __restrict__ csr_src) {
    int e = blockIdx.x * 256 + threadIdx.x;
    int d = ei[E_EDGES + e];
    int s = ei[e];
    int p = atomicAdd(&cursor[d], 1);
    csr_src[p] = s;
}

// ---------------------------------------------------------------------------
// weight pre-convert fp32 -> bf16 (all 6 weight tensors, all layers)
// segments (elem offsets): gw1 0, gw2 65536, aiw 131072, aow 327680,
//                          mw1 393216, mw2 524288, end 655360
// ---------------------------------------------------------------------------
__global__ __launch_bounds__(256) void wcvt(const float* __restrict__ s0, const float* __restrict__ s1,
                                            const float* __restrict__ s2, const float* __restrict__ s3,
                                            const float* __restrict__ s4, const float* __restrict__ s5,
                                            unsigned short* __restrict__ wbf) {
    int i0 = (blockIdx.x * 256 + threadIdx.x) * 8;
    const float* src; int base;
    if      (i0 < 65536)  { src = s0; base = 0; }
    else if (i0 < 131072) { src = s1; base = 65536; }
    else if (i0 < 327680) { src = s2; base = 131072; }
    else if (i0 < 393216) { src = s3; base = 327680; }
    else if (i0 < 524288) { src = s4; base = 393216; }
    else                  { src = s5; base = 524288; }
    const float* p = src + (i0 - base);
    float t[8];
#pragma unroll
    for (int i = 0; i < 8; ++i) t[i] = p[i];
    *(bf16x8*)(wbf + i0) = pack8(t);
}

// fp32 activation -> bf16 copy (layer-0 x)
__global__ __launch_bounds__(256) void x2bf(const float* __restrict__ x,
                                            unsigned short* __restrict__ xb) {
    int i0 = (blockIdx.x * 256 + threadIdx.x) * 8;
    float t[8];
#pragma unroll
    for (int i = 0; i < 8; ++i) t[i] = x[i0 + i];
    *(bf16x8*)(xb + i0) = pack8(t);
}

// ---------------------------------------------------------------------------
// GIN aggregation: hsum[n] = x[n] + sum_{j in N(n)} x[j], output bf16
// ---------------------------------------------------------------------------
__global__ __launch_bounds__(256) void gather_agg(const float* __restrict__ x,
                                                  const int* __restrict__ rowstart,
                                                  const int* __restrict__ csr_src,
                                                  unsigned int* __restrict__ hsum) {
    const int node = blockIdx.x * 4 + (threadIdx.x >> 6);
    const int lane = threadIdx.x & 63;
    const int beg = rowstart[node], end = rowstart[node + 1];
    float2 self = *(const float2*)(x + (size_t)node * C_DIM + lane * 2);
    float2 acc0 = self, acc1 = {0.f, 0.f};
    int e = beg;
    for (; e + 4 <= end; e += 4) {
        int s0 = csr_src[e], s1 = csr_src[e + 1], s2 = csr_src[e + 2], s3 = csr_src[e + 3];
        float2 v0 = *(const float2*)(x + (size_t)s0 * C_DIM + lane * 2);
        float2 v1 = *(const float2*)(x + (size_t)s1 * C_DIM + lane * 2);
        float2 v2 = *(const float2*)(x + (size_t)s2 * C_DIM + lane * 2);
        float2 v3 = *(const float2*)(x + (size_t)s3 * C_DIM + lane * 2);
        acc0.x += v0.x + v1.x; acc0.y += v0.y + v1.y;
        acc1.x += v2.x + v3.x; acc1.y += v2.y + v3.y;
    }
    for (; e < end; ++e) {
        int s0 = csr_src[e];
        float2 v0 = *(const float2*)(x + (size_t)s0 * C_DIM + lane * 2);
        acc0.x += v0.x; acc0.y += v0.y;
    }
    float ox = acc0.x + acc1.x, oy = acc0.y + acc1.y;
    hsum[(size_t)node * 64 + lane] = (unsigned int)f2bf(ox) | ((unsigned int)f2bf(oy) << 16);
}

// ---------------------------------------------------------------------------
// bf16 MFMA GEMM, LDS-free (operands from L2):
// out[n][j] = act( sum_k Abf[n][k]*Wbf[j][k] + bias[j] (+resid) )
// tile 32 rows x 64 cols, 256 thr = 4 waves (2x2), wave = 16x32.
// grid (J/64, N/32).
// ---------------------------------------------------------------------------
template <int K>
__global__ __launch_bounds__(256, 4) void gemm_bf(const unsigned short* __restrict__ Abf,
                                                  const unsigned short* __restrict__ Wbf,
                                                  const float* __restrict__ bias,
                                                  const float* __restrict__ resid,
                                                  float* __restrict__ outf,
                                                  unsigned short* __restrict__ outb,
                                                  const int J, const int relu) {
    const int tid = threadIdx.x;
    const int wv = tid >> 6;
    const int wr = wv >> 1, wc = wv & 1;
    const int lane = tid & 63, lg = lane >> 4, ll = lane & 15;
    const int rowbase = blockIdx.y * 32 + wr * 16;
    const int colbase = blockIdx.x * 64 + wc * 32;

    const unsigned short* Ap  = Abf + (size_t)(rowbase + ll) * K + lg * 8;
    const unsigned short* Wp0 = Wbf + (size_t)(colbase + ll) * K + lg * 8;
    const unsigned short* Wp1 = Wbf + (size_t)(colbase + 16 + ll) * K + lg * 8;

    f32x4 acc0 = {0.f, 0.f, 0.f, 0.f}, acc1 = {0.f, 0.f, 0.f, 0.f};
#pragma unroll
    for (int k = 0; k < K; k += 32) {
        bf16x8 a  = *(const bf16x8*)(Ap + k);
        bf16x8 b0 = *(const bf16x8*)(Wp0 + k);
        bf16x8 b1 = *(const bf16x8*)(Wp1 + k);
        acc0 = __builtin_amdgcn_mfma_f32_16x16x32_bf16(a, b0, acc0, 0, 0, 0);
        acc1 = __builtin_amdgcn_mfma_f32_16x16x32_bf16(a, b1, acc1, 0, 0, 0);
    }

    const int col0 = colbase + ll, col1 = colbase + 16 + ll;
    const float bi0 = bias[col0], bi1 = bias[col1];
#pragma unroll
    for (int r = 0; r < 4; ++r) {
        const int row = rowbase + lg * 4 + r;
        float v0 = acc0[r] + bi0;
        float v1 = acc1[r] + bi1;
        if (resid) {
            v0 += resid[(size_t)row * J + col0];
            v1 += resid[(size_t)row * J + col1];
        }
        if (relu) { v0 = fmaxf(v0, 0.f); v1 = fmaxf(v1, 0.f); }
        if (outf) {
            outf[(size_t)row * J + col0] = v0;
            outf[(size_t)row * J + col1] = v1;
        }
        if (outb) {
            outb[(size_t)row * J + col0] = f2bf(v0);
            outb[(size_t)row * J + col1] = f2bf(v1);
        }
    }
}

// ---------------------------------------------------------------------------
// QKV GEMM (bf16 MFMA, LDS-free) with layout epilogue:
//   Qb [H][N][32] (pre-scaled by 1/sqrt(d)*log2e), Kb [H][N][32], VT [H][32][N]
// grid (6, 128); K=128, J=384.
// ---------------------------------------------------------------------------
__global__ __launch_bounds__(256, 4) void gemm_qkv_bf(const unsigned short* __restrict__ Abf,
                                                      const unsigned short* __restrict__ Wbf,
                                                      const float* __restrict__ bias,
                                                      unsigned short* __restrict__ Qb,
                                                      unsigned short* __restrict__ Kb,
                                                      unsigned short* __restrict__ VT) {
    const int tid = threadIdx.x;
    const int wv = tid >> 6;
    const int wr = wv >> 1, wc = wv & 1;
    const int lane = tid & 63, lg = lane >> 4, ll = lane & 15;
    const int rowbase = blockIdx.y * 32 + wr * 16;
    const int colbase = blockIdx.x * 64 + wc * 32;

    const unsigned short* Ap  = Abf + (size_t)(rowbase + ll) * 128 + lg * 8;
    const unsigned short* Wp0 = Wbf + (size_t)(colbase + ll) * 128 + lg * 8;
    const unsigned short* Wp1 = Wbf + (size_t)(colbase + 16 + ll) * 128 + lg * 8;

    f32x4 acc0 = {0.f, 0.f, 0.f, 0.f}, acc1 = {0.f, 0.f, 0.f, 0.f};
#pragma unroll
    for (int k = 0; k < 128; k += 32) {
        bf16x8 a  = *(const bf16x8*)(Ap + k);
        bf16x8 b0 = *(const bf16x8*)(Wp0 + k);
        bf16x8 b1 = *(const bf16x8*)(Wp1 + k);
        acc0 = __builtin_amdgcn_mfma_f32_16x16x32_bf16(a, b0, acc0, 0, 0, 0);
        acc1 = __builtin_amdgcn_mfma_f32_16x16x32_bf16(a, b1, acc1, 0, 0, 0);
    }

    const float qsc = 0.25506973f;  // (1/sqrt(32)) * log2(e)
#pragma unroll
    for (int c = 0; c < 2; ++c) {
        const int col = colbase + c * 16 + ll;
        const float bi = bias[col];
        f32x4 ac = c ? acc1 : acc0;
#pragma unroll
        for (int r = 0; r < 4; ++r) {
            const int row = rowbase + lg * 4 + r;
            float v = ac[r] + bi;
            if (col < 128) {
                int hh = col >> 5, d = col & 31;
                Qb[((size_t)hh * N_NODES + row) * D_HEAD + d] = f2bf(v * qsc);
            } else if (col < 256) {
                int c2 = col - 128, hh = c2 >> 5, d = c2 & 31;
                Kb[((size_t)hh * N_NODES + row) * D_HEAD + d] = f2bf(v);
            } else {
                int c2 = col - 256, hh = c2 >> 5, d = c2 & 31;
                VT[((size_t)hh * D_HEAD + d) * N_NODES + row] = f2bf(v);
            }
        }
    }
}

// ---------------------------------------------------------------------------
// Flash attention v3: grid (N/16, H), 512 threads = 8 waves.
// All waves share 16 q-rows; each wave owns a 512-key range (4 tiles of 128).
// No max-subtraction (scores bounded ~|3|: exp2 safe in fp32, math identical).
// K/V frags from global (L2). P via wave-private LDS (stride 136 - R4 fix).
// Output written directly as bf16 [N][C] for the aout GEMM.
// ---------------------------------------------------------------------------
__global__ __launch_bounds__(512) void attn_kernel(const unsigned short* __restrict__ Qb,
                                                   const unsigned short* __restrict__ Kb,
                                                   const unsigned short* __restrict__ VT,
                                                   unsigned short* __restrict__ ob) {
    __shared__ __align__(16) unsigned short Pl[8 * 16 * P_STRIDE];
    __shared__ __align__(16) float Ouns[8][16][33];
    __shared__ float Ll[8][16];

    const int h   = blockIdx.y;
    const int q0  = blockIdx.x * 16;
    const int tid = threadIdx.x;
    const int wv  = tid >> 6;
    const int lane = tid & 63;
    const int lg  = lane >> 4;
    const int ll  = lane & 15;

    const unsigned short* Qh = Qb + ((size_t)h * N_NODES + q0) * D_HEAD;
    const unsigned short* Kh = Kb + (size_t)h * N_NODES * D_HEAD;
    const unsigned short* Vh = VT + (size_t)h * D_HEAD * N_NODES;

    bf16x8 qf = *(const bf16x8*)(Qh + ll * D_HEAD + lg * 8);

    f32x4 oacc0 = {0.f, 0.f, 0.f, 0.f};
    f32x4 oacc1 = {0.f, 0.f, 0.f, 0.f};
    float l_r[4] = {0.f, 0.f, 0.f, 0.f};

    unsigned short* Pw = Pl + wv * (16 * P_STRIDE);
    const int k0 = wv * (N_NODES / 8);

    for (int t = 0; t < (N_NODES / 8) / 128; ++t) {
        const int kt = k0 + t * 128;

        bf16x8 vf[8];
#pragma unroll
        for (int kc2 = 0; kc2 < 4; ++kc2) {
            vf[kc2 * 2]     = *(const bf16x8*)(Vh + (size_t)ll * N_NODES + kt + kc2 * 32 + lg * 8);
            vf[kc2 * 2 + 1] = *(const bf16x8*)(Vh + (size_t)(16 + ll) * N_NODES + kt + kc2 * 32 + lg * 8);
        }

        float s[8][4];
#pragma unroll
        for (int kc = 0; kc < 8; ++kc) {
            bf16x8 kf = *(const bf16x8*)(Kh + (size_t)(kt + kc * 16 + ll) * D_HEAD + lg * 8);
            f32x4 z = {0.f, 0.f, 0.f, 0.f};
            f32x4 d = __builtin_amdgcn_mfma_f32_16x16x32_bf16(qf, kf, z, 0, 0, 0);
#pragma unroll
            for (int r = 0; r < 4; ++r) s[kc][r] = d[r];
        }

        // softmax numerator (no max shift needed; scores bounded)
#pragma unroll
        for (int r = 0; r < 4; ++r) {
            float ls = 0.f;
#pragma unroll
            for (int kc = 0; kc < 8; ++kc) {
                float p = exp2f(s[kc][r]);
                s[kc][r] = p;
                ls += p;
            }
#pragma unroll
            for (int off = 1; off < 16; off <<= 1) ls += __shfl_xor(ls, off, 64);
            l_r[r] += ls;
        }

#pragma unroll
        for (int kc = 0; kc < 8; ++kc)
#pragma unroll
            for (int r = 0; r < 4; ++r)
                Pw[(lg * 4 + r) * P_STRIDE + kc * 16 + ll] = f2bf(s[kc][r]);
        asm volatile("" ::: "memory");   // same-wave DS ordering

#pragma unroll
        for (int kc2 = 0; kc2 < 4; ++kc2) {
            bf16x8 pf = *(const bf16x8*)(Pw + ll * P_STRIDE + kc2 * 32 + lg * 8);
            oacc0 = __builtin_amdgcn_mfma_f32_16x16x32_bf16(pf, vf[kc2 * 2],     oacc0, 0, 0, 0);
            oacc1 = __builtin_amdgcn_mfma_f32_16x16x32_bf16(pf, vf[kc2 * 2 + 1], oacc1, 0, 0, 0);
        }
    }

#pragma unroll
    for (int r = 0; r < 4; ++r) {
        Ouns[wv][lg * 4 + r][ll]      = oacc0[r];
        Ouns[wv][lg * 4 + r][16 + ll] = oacc1[r];
    }
    if (ll == 0) {
#pragma unroll
        for (int r = 0; r < 4; ++r) Ll[wv][lg * 4 + r] = l_r[r];
    }
    __syncthreads();

    // merge 8 key-split partials; 512 threads = 16 rows x 32 cols
    {
        const int row = tid >> 5, col = tid & 31;
        float L = 0.f, o = 0.f;
#pragma unroll
        for (int w = 0; w < 8; ++w) { L += Ll[w][row]; o += Ouns[w][row][col]; }
        ob[(size_t)(q0 + row) * C_DIM + h * D_HEAD + col] = f2bf(o / L);
    }
}

// ---------------------------------------------------------------------------
// BatchNorm stats (fp32 inputs): ss[c]=g*rstd ; ss[C+c]=b-mean*scale
// ---------------------------------------------------------------------------
__global__ __launch_bounds__(256) void bn_stats(const float* __restrict__ in,
                                                const float* __restrict__ g,
                                                const float* __restrict__ b,
                                                float* __restrict__ ss) {
    const int c4 = blockIdx.x;
    const int tid = threadIdx.x;
    float s[4] = {0.f, 0.f, 0.f, 0.f}, s2[4] = {0.f, 0.f, 0.f, 0.f};
    for (int r = tid; r < N_NODES; r += 256) {
        float4 v = *(const float4*)(in + (size_t)r * C_DIM + c4 * 4);
        s[0] += v.x; s2[0] += v.x * v.x;
        s[1] += v.y; s2[1] += v.y * v.y;
        s[2] += v.z; s2[2] += v.z * v.z;
        s[3] += v.w; s2[3] += v.w * v.w;
    }
#pragma unroll
    for (int off = 1; off < 64; off <<= 1) {
#pragma unroll
        for (int c = 0; c < 4; ++c) {
            s[c]  += __shfl_xor(s[c],  off, 64);
            s2[c] += __shfl_xor(s2[c], off, 64);
        }
    }
    __shared__ float red[4][8];
    int w = tid >> 6;
    if ((tid & 63) == 0) {
#pragma unroll
        for (int c = 0; c < 4; ++c) { red[w][c] = s[c]; red[w][4 + c] = s2[c]; }
    }
    __syncthreads();
    if (tid == 0) {
#pragma unroll
        for (int c = 0; c < 4; ++c) {
            float fs = red[0][c] + red[1][c] + red[2][c] + red[3][c];
            float fs2 = red[0][4 + c] + red[1][4 + c] + red[2][4 + c] + red[3][4 + c];
            int ch = c4 * 4 + c;
            float mean = fs / N_NODES;
            float var = fs2 / N_NODES - mean * mean;
            float rstd = rsqrtf(var + 1e-5f);
            float scale = g[ch] * rstd;
            ss[ch] = scale;
            ss[C_DIM + ch] = b[ch] - mean * scale;
        }
    }
}

// h = bn1(g1)+bn2(a2); fp32 out + bf16 out
__global__ __launch_bounds__(256) void combine2(const float* __restrict__ p1,
                                                const float* __restrict__ p2,
                                                const float* __restrict__ ss1,
                                                const float* __restrict__ ss2,
                                                float* __restrict__ out,
                                                unsigned short* __restrict__ outb) {
    int idx = blockIdx.x * 256 + threadIdx.x;
    int c4 = (idx & 31) * 4;
    float4 v1 = ((const float4*)p1)[idx];
    float4 v2 = ((const float4*)p2)[idx];
    float4 sc1 = *(const float4*)(ss1 + c4), sh1 = *(const float4*)(ss1 + C_DIM + c4);
    float4 sc2 = *(const float4*)(ss2 + c4), sh2 = *(const float4*)(ss2 + C_DIM + c4);
    float4 o;
    o.x = v1.x * sc1.x + sh1.x + v2.x * sc2.x + sh2.x;
    o.y = v1.y * sc1.y + sh1.y + v2.y * sc2.y + sh2.y;
    o.z = v1.z * sc1.z + sh1.z + v2.z * sc2.z + sh2.z;
    o.w = v1.w * sc1.w + sh1.w + v2.w * sc2.w + sh2.w;
    ((float4*)out)[idx] = o;
    ushort4 ub;
    ub.x = f2bf(o.x); ub.y = f2bf(o.y); ub.z = f2bf(o.z); ub.w = f2bf(o.w);
    *(ushort4*)(outb + (size_t)idx * 4) = ub;
}

// x = bn3(m3); fp32 out + bf16 out
__global__ __launch_bounds__(256) void bn_apply(const float* __restrict__ p,
                                                const float* __restrict__ ss,
                                                float* __restrict__ out,
                                                unsigned short* __restrict__ outb) {
    int idx = blockIdx.x * 256 + threadIdx.x;
    int c4 = (idx & 31) * 4;
    float4 v = ((const float4*)p)[idx];
    float4 sc = *(const float4*)(ss + c4), sh = *(const float4*)(ss + C_DIM + c4);
    float4 o;
    o.x = v.x * sc.x + sh.x;
    o.y = v.y * sc.y + sh.y;
    o.z = v.z * sc.z + sh.z;
    o.w = v.w * sc.w + sh.w;
    ((float4*)out)[idx] = o;
    ushort4 ub;
    ub.x = f2bf(o.x); ub.y = f2bf(o.y); ub.z = f2bf(o.z); ub.w = f2bf(o.w);
    *(ushort4*)(outb + (size_t)idx * 4) = ub;
}

// ---------------------------------------------------------------------------
// head layer 1 (fp32, small): kept from R2 (64x64 tile), J=64
// ---------------------------------------------------------------------------
template <int K>
__global__ __launch_bounds__(256) void gemm_f32(const float* __restrict__ A,
                                                const float* __restrict__ W,
                                                const float* __restrict__ bias,
                                                float* __restrict__ out,
                                                const int J, const int relu) {
    __shared__ __align__(16) float As[64 * 132];
    __shared__ __align__(16) float Ws[64 * 132];
    const int tid = threadIdx.x;
    const int ct = blockIdx.x, rt = blockIdx.y;
    const int tc = tid & 15, tr = tid >> 4;
    float acc[4][4] = {};

    for (int kc = 0; kc < K; kc += 128) {
        if (kc) __syncthreads();
#pragma unroll
        for (int i = 0; i < 8; ++i) {
            int idx = tid + i * 256;
            int r = idx >> 5, kq = idx & 31;
            *(float4*)(As + r * 132 + kq * 4) =
                *(const float4*)(A + (size_t)(rt * 64 + r) * K + kc + kq * 4);
            *(float4*)(Ws + r * 132 + kq * 4) =
                *(const float4*)(W + (size_t)(ct * 64 + r) * K + kc + kq * 4);
        }
        __syncthreads();
#pragma unroll 4
        for (int k4 = 0; k4 < 32; ++k4) {
            float4 a[4], w[4];
#pragma unroll
            for (int i = 0; i < 4; ++i) a[i] = *(const float4*)(As + (tr * 4 + i) * 132 + k4 * 4);
#pragma unroll
            for (int j = 0; j < 4; ++j) w[j] = *(const float4*)(Ws + (tc * 4 + j) * 132 + k4 * 4);
#pragma unroll
            for (int i = 0; i < 4; ++i)
#pragma unroll
                for (int j = 0; j < 4; ++j)
                    acc[i][j] += a[i].x * w[j].x + a[i].y * w[j].y +
                                 a[i].z * w[j].z + a[i].w * w[j].w;
        }
    }

#pragma unroll
    for (int i = 0; i < 4; ++i) {
        int row = rt * 64 + tr * 4 + i;
        float4 o4;
        float* po = (float*)&o4;
#pragma unroll
        for (int j = 0; j < 4; ++j) {
            int col = ct * 64 + tc * 4 + j;
            float v = acc[i][j] + bias[col];
            if (relu) v = fmaxf(v, 0.f);
            po[j] = v;
        }
        *(float4*)(out + (size_t)row * J + ct * 64 + tc * 4) = o4;
    }
}

__global__ __launch_bounds__(256) void head23(const float* __restrict__ hh1,
                                              const float* __restrict__ w2,
                                              const float* __restrict__ b2,
                                              const float* __restrict__ w3,
                                              const float* __restrict__ b3,
                                              float* __restrict__ out) {
    int n = blockIdx.x * 256 + threadIdx.x;
    float4 r[16];
#pragma unroll
    for (int q = 0; q < 16; ++q) r[q] = *(const float4*)(hh1 + (size_t)n * 64 + q * 4);
    float acc = b3[0];
#pragma unroll 4
    for (int j = 0; j < 32; ++j) {
        float sv = b2[j];
#pragma unroll
        for (int q = 0; q < 16; ++q) {
            float4 wr = *(const float4*)(w2 + j * 64 + q * 4);
            sv += r[q].x * wr.x + r[q].y * wr.y + r[q].z * wr.z + r[q].w * wr.w;
        }
        acc += fmaxf(sv, 0.f) * w3[j];
    }
    out[n] = acc;
}

// ---------------------------------------------------------------------------
extern "C" void kernel_launch(void* const* d_in, const int* in_sizes, int n_in,
                              void* d_out, int out_size, void* d_ws, size_t ws_size,
                              hipStream_t stream) {
    (void)in_sizes; (void)n_in; (void)out_size; (void)ws_size;
    const float* x_in   = (const float*)d_in[0];
    const int*   ei     = (const int*)d_in[1];
    const float* gin_w1 = (const float*)d_in[2];
    const float* gin_b1 = (const float*)d_in[3];
    const float* gin_w2 = (const float*)d_in[4];
    const float* gin_b2 = (const float*)d_in[5];
    const float* ain_w  = (const float*)d_in[6];
    const float* ain_b  = (const float*)d_in[7];
    const float* aout_w = (const float*)d_in[8];
    const float* aout_b = (const float*)d_in[9];
    const float* n1_g   = (const float*)d_in[10];
    const float* n1_b   = (const float*)d_in[11];
    const float* n2_g   = (const float*)d_in[12];
    const float* n2_b   = (const float*)d_in[13];
    const float* n3_g   = (const float*)d_in[14];
    const float* n3_b   = (const float*)d_in[15];
    const float* mlp_w1 = (const float*)d_in[16];
    const float* mlp_b1 = (const float*)d_in[17];
    const float* mlp_w2 = (const float*)d_in[18];
    const float* mlp_b2 = (const float*)d_in[19];
    const float* h_w1   = (const float*)d_in[20];
    const float* h_b1   = (const float*)d_in[21];
    const float* h_w2   = (const float*)d_in[22];
    const float* h_b2   = (const float*)d_in[23];
    const float* h_w3   = (const float*)d_in[24];
    const float* h_b3   = (const float*)d_in[25];

    float* f = (float*)d_ws;
    // fp32 chunks (NC floats each)
    float* g1   = f;                 // c0; m3 aliases (g1 dead after combine2)
    float* m3   = f;
    float* a2   = f + 1 * (size_t)NC;  // c1; hh1 aliases after layers
    float* hh1  = f + 1 * (size_t)NC;
    float* hbuf = f + 2 * (size_t)NC;
    float* xA   = f + 3 * (size_t)NC;
    float* xB   = f + 4 * (size_t)NC;
    // bf16 regions
    unsigned short* R1  = (unsigned short*)(f + 5 * (size_t)NC);  // 3 NCu
    unsigned short* hsum_bf = R1;                 // [N][128]
    unsigned short* t1_bf   = R1 + (size_t)NCu;   // [N][128]
    unsigned short* Qb      = R1;                 // after gin2: QKV overwrite
    unsigned short* Kb      = R1 + (size_t)NCu;
    unsigned short* VT      = R1 + 2 * (size_t)NCu;
    unsigned short* t2_bf   = R1;                 // [N][256] after attn+aout
    unsigned short* R2      = R1 + 3 * (size_t)NCu;  // 1 NCu
    unsigned short* ao_bf   = R2;                 // attn out bf16
    unsigned short* hbuf_bf = R2;                 // after aout
    unsigned short* xbf     = R2 + (size_t)NCu;   // 1 NCu
    unsigned short* wbf     = xbf + (size_t)NCu;  // 655360 ushorts
    float* ss    = (float*)(wbf + 655360);        // 768 floats
    int* ibase    = (int*)(ss + 768);
    int* deg      = ibase;
    int* rowstart = ibase + 4096;
    int* cursor   = ibase + 4096 + 4098;
    int* csr_src  = ibase + 4096 + 4098 + 4096;

    // weight offsets in wbf (ushort elems)
    const int OG1 = 0, OG2 = 65536, OAI = 131072, OAO = 327680, OM1 = 393216, OM2 = 524288;

    // one-time per launch: CSR + weight/x conversion
    hipMemsetAsync(deg, 0, 4096 * sizeof(int), stream);
    hist_kernel<<<E_EDGES / 256, 256, 0, stream>>>(ei, deg);
    scan_kernel<<<1, 256, 0, stream>>>(deg, rowstart, cursor);
    fill_kernel<<<E_EDGES / 256, 256, 0, stream>>>(ei, cursor, csr_src);
    wcvt<<<320, 256, 0, stream>>>(gin_w1, gin_w2, ain_w, aout_w, mlp_w1, mlp_w2, wbf);
    x2bf<<<NC / 2048, 256, 0, stream>>>(x_in, xbf);

    for (int i = 0; i < L_LAYERS; ++i) {
        const float* xin = (i == 0) ? x_in : ((i & 1) ? xA : xB);
        float* xout = (i & 1) ? xB : xA;
        const float* gb1 = gin_b1 + (size_t)i * C_DIM;
        const float* gb2 = gin_b2 + (size_t)i * C_DIM;
        const float* aib = ain_b + (size_t)i * 3 * C_DIM;
        const float* aob = aout_b + (size_t)i * C_DIM;
        const float* mb1 = mlp_b1 + (size_t)i * 2 * C_DIM;
        const float* mb2 = mlp_b2 + (size_t)i * C_DIM;

        // GIN branch
        gather_agg<<<N_NODES / 4, 256, 0, stream>>>(xin, rowstart, csr_src, (unsigned int*)hsum_bf);
        gemm_bf<128><<<dim3(2, 128), 256, 0, stream>>>(hsum_bf, wbf + OG1 + (size_t)i * 16384,
                                                       gb1, nullptr, nullptr, t1_bf, 128, 1);
        gemm_bf<128><<<dim3(2, 128), 256, 0, stream>>>(t1_bf, wbf + OG2 + (size_t)i * 16384,
                                                       gb2, xin, g1, nullptr, 128, 0);
        // attention branch
        gemm_qkv_bf<<<dim3(6, 128), 256, 0, stream>>>(xbf, wbf + OAI + (size_t)i * 49152,
                                                      aib, Qb, Kb, VT);
        attn_kernel<<<dim3(N_NODES / 16, H_HEADS), 512, 0, stream>>>(Qb, Kb, VT, ao_bf);
        gemm_bf<128><<<dim3(2, 128), 256, 0, stream>>>(ao_bf, wbf + OAO + (size_t)i * 16384,
                                                       aob, xin, a2, nullptr, 128, 0);
        // norms + combine
        bn_stats<<<32, 256, 0, stream>>>(g1, n1_g + (size_t)i * C_DIM, n1_b + (size_t)i * C_DIM, ss);
        bn_stats<<<32, 256, 0, stream>>>(a2, n2_g + (size_t)i * C_DIM, n2_b + (size_t)i * C_DIM, ss + 256);
        combine2<<<512, 256, 0, stream>>>(g1, a2, ss, ss + 256, hbuf, hbuf_bf);
        // MLP
        gemm_bf<128><<<dim3(4, 128), 256, 0, stream>>>(hbuf_bf, wbf + OM1 + (size_t)i * 32768,
                                                       mb1, nullptr, nullptr, t2_bf, 256, 1);
        gemm_bf<256><<<dim3(2, 128), 256, 0, stream>>>(t2_bf, wbf + OM2 + (size_t)i * 32768,
                                                       mb2, hbuf, m3, nullptr, 128, 0);
        bn_stats<<<32, 256, 0, stream>>>(m3, n3_g + (size_t)i * C_DIM, n3_b + (size_t)i * C_DIM, ss + 512);
        bn_apply<<<512, 256, 0, stream>>>(m3, ss + 512, xout, xbf);
    }

    const float* xf = xB;  // after layer 3
    gemm_f32<128><<<dim3(1, 64), 256, 0, stream>>>(xf, h_w1, h_b1, hh1, 64, 1);
    head23<<<16, 256, 0, stream>>>(hh1, h_w2, h_b2, h_w3, h_b3, (float*)d_out);
}

// Round 6
// 505.038 us; speedup vs baseline: 3.5933x; 1.1445x over previous
//
#include <hip/hip_runtime.h>

#define N_NODES 4096
#define C_DIM   128
#define L_LAYERS 4
#define E_EDGES 131072
#define H_HEADS 4
#define D_HEAD  32
#define NC      (N_NODES * C_DIM)
#define NCu     (N_NODES * C_DIM)
#define P_STRIDE 136

typedef short bf16x8 __attribute__((ext_vector_type(8)));
typedef float f32x4  __attribute__((ext_vector_type(4)));

__device__ __forceinline__ unsigned short f2bf(float f) {
    unsigned int u = __float_as_uint(f);
    u += 0x7fffu + ((u >> 16) & 1u);
    return (unsigned short)(u >> 16);
}

__device__ __forceinline__ bf16x8 pack8(const float* v) {
    bf16x8 o;
#pragma unroll
    for (int i = 0; i < 8; ++i) o[i] = (short)f2bf(v[i]);
    return o;
}

// ---------------------------------------------------------------------------
// CSR build (once per launch)
// ---------------------------------------------------------------------------
__global__ __launch_bounds__(256) void hist_kernel(const int* __restrict__ ei,
                                                   int* __restrict__ deg) {
    int e = blockIdx.x * 256 + threadIdx.x;
    atomicAdd(&deg[ei[E_EDGES + e]], 1);
}

__global__ __launch_bounds__(256) void scan_kernel(const int* __restrict__ deg,
                                                   int* __restrict__ rowstart,
                                                   int* __restrict__ cursor) {
    __shared__ int ts[256];
    const int tid = threadIdx.x;
    int loc[16];
    int s = 0;
#pragma unroll
    for (int i = 0; i < 16; ++i) { loc[i] = s; s += deg[tid * 16 + i]; }
    ts[tid] = s;
    __syncthreads();
    for (int off = 1; off < 256; off <<= 1) {
        int t = (tid >= off) ? ts[tid - off] : 0;
        __syncthreads();
        if (tid >= off) ts[tid] += t;
        __syncthreads();
    }
    int off0 = ts[tid] - s;
#pragma unroll
    for (int i = 0; i < 16; ++i) {
        int v = off0 + loc[i];
        rowstart[tid * 16 + i] = v;
        cursor[tid * 16 + i] = v;
    }
    if (tid == 255) rowstart[4096] = off0 + s;
}

__global__ __launch_bounds__(256) void fill_kernel(const int* __restrict__ ei,
                                                   int* __restrict__ cursor,
                                                   int* __restrict__ csr_src) {
    int e = blockIdx.x * 256 + threadIdx.x;
    int d = ei[E_EDGES + e];
    int s = ei[e];
    int p = atomicAdd(&cursor[d], 1);
    csr_src[p] = s;
}

// ---------------------------------------------------------------------------
// weight pre-convert fp32 -> bf16
// ---------------------------------------------------------------------------
__global__ __launch_bounds__(256) void wcvt(const float* __restrict__ s0, const float* __restrict__ s1,
                                            const float* __restrict__ s2, const float* __restrict__ s3,
                                            const float* __restrict__ s4, const float* __restrict__ s5,
                                            unsigned short* __restrict__ wbf) {
    int i0 = (blockIdx.x * 256 + threadIdx.x) * 8;
    const float* src; int base;
    if      (i0 < 65536)  { src = s0; base = 0; }
    else if (i0 < 131072) { src = s1; base = 65536; }
    else if (i0 < 327680) { src = s2; base = 131072; }
    else if (i0 < 393216) { src = s3; base = 327680; }
    else if (i0 < 524288) { src = s4; base = 393216; }
    else                  { src = s5; base = 524288; }
    const float* p = src + (i0 - base);
    float t[8];
#pragma unroll
    for (int i = 0; i < 8; ++i) t[i] = p[i];
    *(bf16x8*)(wbf + i0) = pack8(t);
}

__global__ __launch_bounds__(256) void x2bf(const float* __restrict__ x,
                                            unsigned short* __restrict__ xb) {
    int i0 = (blockIdx.x * 256 + threadIdx.x) * 8;
    float t[8];
#pragma unroll
    for (int i = 0; i < 8; ++i) t[i] = x[i0 + i];
    *(bf16x8*)(xb + i0) = pack8(t);
}

// ---------------------------------------------------------------------------
// GIN aggregation: hsum[n] = x[n] + sum_{j in N(n)} x[j], output bf16
// ---------------------------------------------------------------------------
__global__ __launch_bounds__(256) void gather_agg(const float* __restrict__ x,
                                                  const int* __restrict__ rowstart,
                                                  const int* __restrict__ csr_src,
                                                  unsigned int* __restrict__ hsum) {
    const int node = blockIdx.x * 4 + (threadIdx.x >> 6);
    const int lane = threadIdx.x & 63;
    const int beg = rowstart[node], end = rowstart[node + 1];
    float2 self = *(const float2*)(x + (size_t)node * C_DIM + lane * 2);
    float2 acc0 = self, acc1 = {0.f, 0.f};
    int e = beg;
    for (; e + 4 <= end; e += 4) {
        int s0 = csr_src[e], s1 = csr_src[e + 1], s2 = csr_src[e + 2], s3 = csr_src[e + 3];
        float2 v0 = *(const float2*)(x + (size_t)s0 * C_DIM + lane * 2);
        float2 v1 = *(const float2*)(x + (size_t)s1 * C_DIM + lane * 2);
        float2 v2 = *(const float2*)(x + (size_t)s2 * C_DIM + lane * 2);
        float2 v3 = *(const float2*)(x + (size_t)s3 * C_DIM + lane * 2);
        acc0.x += v0.x + v1.x; acc0.y += v0.y + v1.y;
        acc1.x += v2.x + v3.x; acc1.y += v2.y + v3.y;
    }
    for (; e < end; ++e) {
        int s0 = csr_src[e];
        float2 v0 = *(const float2*)(x + (size_t)s0 * C_DIM + lane * 2);
        acc0.x += v0.x; acc0.y += v0.y;
    }
    float ox = acc0.x + acc1.x, oy = acc0.y + acc1.y;
    hsum[(size_t)node * 64 + lane] = (unsigned int)f2bf(ox) | ((unsigned int)f2bf(oy) << 16);
}

// ---------------------------------------------------------------------------
// bf16 MFMA GEMM v2, LDS-free, 16x16 tile per wave for max occupancy.
// grid (J/64, N/16), 256 thr = 4 waves; wave wv covers cols bx*64+wv*16.
// ---------------------------------------------------------------------------
template <int K>
__global__ __launch_bounds__(256, 8) void gemm_bf(const unsigned short* __restrict__ Abf,
                                                  const unsigned short* __restrict__ Wbf,
                                                  const float* __restrict__ bias,
                                                  const float* __restrict__ resid,
                                                  float* __restrict__ outf,
                                                  unsigned short* __restrict__ outb,
                                                  const int J, const int relu) {
    const int tid = threadIdx.x;
    const int wv = tid >> 6;
    const int lane = tid & 63, lg = lane >> 4, ll = lane & 15;
    const int rowbase = blockIdx.y * 16;
    const int colbase = blockIdx.x * 64 + wv * 16;

    const unsigned short* Ap = Abf + (size_t)(rowbase + ll) * K + lg * 8;
    const unsigned short* Wp = Wbf + (size_t)(colbase + ll) * K + lg * 8;

    f32x4 acc = {0.f, 0.f, 0.f, 0.f};
#pragma unroll
    for (int k = 0; k < K; k += 32) {
        bf16x8 a = *(const bf16x8*)(Ap + k);
        bf16x8 b = *(const bf16x8*)(Wp + k);
        acc = __builtin_amdgcn_mfma_f32_16x16x32_bf16(a, b, acc, 0, 0, 0);
    }

    const int col = colbase + ll;
    const float bi = bias[col];
#pragma unroll
    for (int r = 0; r < 4; ++r) {
        const int row = rowbase + lg * 4 + r;
        float v = acc[r] + bi;
        if (resid) v += resid[(size_t)row * J + col];
        if (relu) v = fmaxf(v, 0.f);
        if (outf) outf[(size_t)row * J + col] = v;
        if (outb) outb[(size_t)row * J + col] = f2bf(v);
    }
}

// ---------------------------------------------------------------------------
// QKV GEMM v2 with layout epilogue: Qb [H][N][32] (pre-scaled), Kb [H][N][32],
// VT [H][32][N].  grid (6, 256).
// ---------------------------------------------------------------------------
__global__ __launch_bounds__(256, 8) void gemm_qkv_bf(const unsigned short* __restrict__ Abf,
                                                      const unsigned short* __restrict__ Wbf,
                                                      const float* __restrict__ bias,
                                                      unsigned short* __restrict__ Qb,
                                                      unsigned short* __restrict__ Kb,
                                                      unsigned short* __restrict__ VT) {
    const int tid = threadIdx.x;
    const int wv = tid >> 6;
    const int lane = tid & 63, lg = lane >> 4, ll = lane & 15;
    const int rowbase = blockIdx.y * 16;
    const int colbase = blockIdx.x * 64 + wv * 16;

    const unsigned short* Ap = Abf + (size_t)(rowbase + ll) * 128 + lg * 8;
    const unsigned short* Wp = Wbf + (size_t)(colbase + ll) * 128 + lg * 8;

    f32x4 acc = {0.f, 0.f, 0.f, 0.f};
#pragma unroll
    for (int k = 0; k < 128; k += 32) {
        bf16x8 a = *(const bf16x8*)(Ap + k);
        bf16x8 b = *(const bf16x8*)(Wp + k);
        acc = __builtin_amdgcn_mfma_f32_16x16x32_bf16(a, b, acc, 0, 0, 0);
    }

    const float qsc = 0.25506973f;  // (1/sqrt(32)) * log2(e)
    const int col = colbase + ll;
    const float bi = bias[col];
#pragma unroll
    for (int r = 0; r < 4; ++r) {
        const int row = rowbase + lg * 4 + r;
        float v = acc[r] + bi;
        if (col < 128) {
            int hh = col >> 5, d = col & 31;
            Qb[((size_t)hh * N_NODES + row) * D_HEAD + d] = f2bf(v * qsc);
        } else if (col < 256) {
            int c2 = col - 128, hh = c2 >> 5, d = c2 & 31;
            Kb[((size_t)hh * N_NODES + row) * D_HEAD + d] = f2bf(v);
        } else {
            int c2 = col - 256, hh = c2 >> 5, d = c2 & 31;
            VT[((size_t)hh * D_HEAD + d) * N_NODES + row] = f2bf(v);
        }
    }
}

// ---------------------------------------------------------------------------
// Flash attention v4: grid (N/32, H), 512 thr = 8 waves.
// Block = 32 q-rows. Each wave: 2 q-fragments x 512-key range (8-way split);
// K-frag loaded once feeds 2 QK MFMAs, V-frag feeds 2 PV MFMAs.
// No max-subtraction (scores bounded). P in wave-private LDS (stride 136).
// Merge arrays OVERLAY Pl (barrier-separated) -> 68KB LDS, 2 blocks/CU.
// ---------------------------------------------------------------------------
__global__ __launch_bounds__(512, 4) void attn_kernel(const unsigned short* __restrict__ Qb,
                                                      const unsigned short* __restrict__ Kb,
                                                      const unsigned short* __restrict__ VT,
                                                      unsigned short* __restrict__ ob) {
    __shared__ __align__(16) unsigned short Pl[8 * 32 * P_STRIDE];   // 69632 B
    float (*Ouns)[32][33] = (float (*)[32][33])(void*)Pl;            // 33792 B overlay
    float (*Llp)[32] = (float (*)[32])(void*)(Pl + 8 * 32 * 33 * 2); // +1024 B

    const int h   = blockIdx.y;
    const int q0  = blockIdx.x * 32;
    const int tid = threadIdx.x;
    const int wv  = tid >> 6;
    const int lane = tid & 63;
    const int lg  = lane >> 4;
    const int ll  = lane & 15;

    const unsigned short* Qh = Qb + ((size_t)h * N_NODES + q0) * D_HEAD;
    const unsigned short* Kh = Kb + (size_t)h * N_NODES * D_HEAD;
    const unsigned short* Vh = VT + (size_t)h * D_HEAD * N_NODES;

    bf16x8 qf0 = *(const bf16x8*)(Qh + ll * D_HEAD + lg * 8);
    bf16x8 qf1 = *(const bf16x8*)(Qh + (16 + ll) * D_HEAD + lg * 8);

    f32x4 oacc00 = {0.f,0.f,0.f,0.f}, oacc01 = {0.f,0.f,0.f,0.f};
    f32x4 oacc10 = {0.f,0.f,0.f,0.f}, oacc11 = {0.f,0.f,0.f,0.f};
    float l0[4] = {0.f,0.f,0.f,0.f}, l1[4] = {0.f,0.f,0.f,0.f};

    unsigned short* Pw = Pl + wv * (32 * P_STRIDE);
    const int k0 = wv * (N_NODES / 8);

    for (int t = 0; t < (N_NODES / 8) / 128; ++t) {
        const int kt = k0 + t * 128;

        // QK^T for both q-fragments; each K-frag loaded once
        float s0[8][4], s1[8][4];
#pragma unroll
        for (int kc = 0; kc < 8; ++kc) {
            bf16x8 kf = *(const bf16x8*)(Kh + (size_t)(kt + kc * 16 + ll) * D_HEAD + lg * 8);
            f32x4 z = {0.f, 0.f, 0.f, 0.f};
            f32x4 d0 = __builtin_amdgcn_mfma_f32_16x16x32_bf16(qf0, kf, z, 0, 0, 0);
            f32x4 d1 = __builtin_amdgcn_mfma_f32_16x16x32_bf16(qf1, kf, z, 0, 0, 0);
#pragma unroll
            for (int r = 0; r < 4; ++r) { s0[kc][r] = d0[r]; s1[kc][r] = d1[r]; }
        }

        // softmax numerator (scores bounded -> no max shift)
#pragma unroll
        for (int r = 0; r < 4; ++r) {
            float a = 0.f, b = 0.f;
#pragma unroll
            for (int kc = 0; kc < 8; ++kc) {
                float p0 = exp2f(s0[kc][r]); s0[kc][r] = p0; a += p0;
                float p1 = exp2f(s1[kc][r]); s1[kc][r] = p1; b += p1;
            }
#pragma unroll
            for (int off = 1; off < 16; off <<= 1) {
                a += __shfl_xor(a, off, 64);
                b += __shfl_xor(b, off, 64);
            }
            l0[r] += a;
            l1[r] += b;
        }

        // P -> wave-private LDS (bf16): rows 0-15 qfrag0, 16-31 qfrag1
#pragma unroll
        for (int kc = 0; kc < 8; ++kc)
#pragma unroll
            for (int r = 0; r < 4; ++r) {
                Pw[(lg * 4 + r) * P_STRIDE + kc * 16 + ll]        = f2bf(s0[kc][r]);
                Pw[(16 + lg * 4 + r) * P_STRIDE + kc * 16 + ll]   = f2bf(s1[kc][r]);
            }
        asm volatile("" ::: "memory");   // same-wave DS ordering

        // PV: V-frag loaded once feeds both q-fragments
#pragma unroll
        for (int kc2 = 0; kc2 < 4; ++kc2) {
            bf16x8 va = *(const bf16x8*)(Vh + (size_t)ll * N_NODES + kt + kc2 * 32 + lg * 8);
            bf16x8 vb = *(const bf16x8*)(Vh + (size_t)(16 + ll) * N_NODES + kt + kc2 * 32 + lg * 8);
            bf16x8 pf0 = *(const bf16x8*)(Pw + ll * P_STRIDE + kc2 * 32 + lg * 8);
            bf16x8 pf1 = *(const bf16x8*)(Pw + (16 + ll) * P_STRIDE + kc2 * 32 + lg * 8);
            oacc00 = __builtin_amdgcn_mfma_f32_16x16x32_bf16(pf0, va, oacc00, 0, 0, 0);
            oacc01 = __builtin_amdgcn_mfma_f32_16x16x32_bf16(pf0, vb, oacc01, 0, 0, 0);
            oacc10 = __builtin_amdgcn_mfma_f32_16x16x32_bf16(pf1, va, oacc10, 0, 0, 0);
            oacc11 = __builtin_amdgcn_mfma_f32_16x16x32_bf16(pf1, vb, oacc11, 0, 0, 0);
        }
    }

    __syncthreads();   // everyone done with Pl; overlay becomes valid

#pragma unroll
    for (int r = 0; r < 4; ++r) {
        Ouns[wv][lg * 4 + r][ll]           = oacc00[r];
        Ouns[wv][lg * 4 + r][16 + ll]      = oacc01[r];
        Ouns[wv][16 + lg * 4 + r][ll]      = oacc10[r];
        Ouns[wv][16 + lg * 4 + r][16 + ll] = oacc11[r];
    }
    if (ll == 0) {
#pragma unroll
        for (int r = 0; r < 4; ++r) {
            Llp[wv][lg * 4 + r]      = l0[r];
            Llp[wv][16 + lg * 4 + r] = l1[r];
        }
    }
    __syncthreads();

    // merge 8 key-split partials; 512 thr = 32 rows x 16 cols (2 cols each)
    {
        const int row = tid >> 4, col = tid & 15;
        float L = 0.f, oa = 0.f, obv = 0.f;
#pragma unroll
        for (int w = 0; w < 8; ++w) {
            L   += Llp[w][row];
            oa  += Ouns[w][row][col];
            obv += Ouns[w][row][16 + col];
        }
        float inv = 1.f / L;
        ob[(size_t)(q0 + row) * C_DIM + h * D_HEAD + col]      = f2bf(oa * inv);
        ob[(size_t)(q0 + row) * C_DIM + h * D_HEAD + 16 + col] = f2bf(obv * inv);
    }
}

// ---------------------------------------------------------------------------
// fused double BatchNorm stats: blocks 0-31 -> in1/ss1, 32-63 -> in2/ss2
// ---------------------------------------------------------------------------
__global__ __launch_bounds__(256) void bn_stats2(const float* __restrict__ in1,
                                                 const float* __restrict__ g1v,
                                                 const float* __restrict__ b1v,
                                                 float* __restrict__ ss1,
                                                 const float* __restrict__ in2,
                                                 const float* __restrict__ g2v,
                                                 const float* __restrict__ b2v,
                                                 float* __restrict__ ss2) {
    const int which = blockIdx.x >> 5;
    const int c4 = blockIdx.x & 31;
    const float* in = which ? in2 : in1;
    const float* g  = which ? g2v : g1v;
    const float* b  = which ? b2v : b1v;
    float* ss       = which ? ss2 : ss1;
    const int tid = threadIdx.x;
    float s[4] = {0.f,0.f,0.f,0.f}, s2[4] = {0.f,0.f,0.f,0.f};
    for (int r = tid; r < N_NODES; r += 256) {
        float4 v = *(const float4*)(in + (size_t)r * C_DIM + c4 * 4);
        s[0] += v.x; s2[0] += v.x * v.x;
        s[1] += v.y; s2[1] += v.y * v.y;
        s[2] += v.z; s2[2] += v.z * v.z;
        s[3] += v.w; s2[3] += v.w * v.w;
    }
#pragma unroll
    for (int off = 1; off < 64; off <<= 1) {
#pragma unroll
        for (int c = 0; c < 4; ++c) {
            s[c]  += __shfl_xor(s[c],  off, 64);
            s2[c] += __shfl_xor(s2[c], off, 64);
        }
    }
    __shared__ float red[4][8];
    int w = tid >> 6;
    if ((tid & 63) == 0) {
#pragma unroll
        for (int c = 0; c < 4; ++c) { red[w][c] = s[c]; red[w][4 + c] = s2[c]; }
    }
    __syncthreads();
    if (tid == 0) {
#pragma unroll
        for (int c = 0; c < 4; ++c) {
            float fs = red[0][c] + red[1][c] + red[2][c] + red[3][c];
            float fs2 = red[0][4 + c] + red[1][4 + c] + red[2][4 + c] + red[3][4 + c];
            int ch = c4 * 4 + c;
            float mean = fs / N_NODES;
            float var = fs2 / N_NODES - mean * mean;
            float rstd = rsqrtf(var + 1e-5f);
            float scale = g[ch] * rstd;
            ss[ch] = scale;
            ss[C_DIM + ch] = b[ch] - mean * scale;
        }
    }
}

__global__ __launch_bounds__(256) void bn_stats(const float* __restrict__ in,
                                                const float* __restrict__ g,
                                                const float* __restrict__ b,
                                                float* __restrict__ ss) {
    const int c4 = blockIdx.x;
    const int tid = threadIdx.x;
    float s[4] = {0.f,0.f,0.f,0.f}, s2[4] = {0.f,0.f,0.f,0.f};
    for (int r = tid; r < N_NODES; r += 256) {
        float4 v = *(const float4*)(in + (size_t)r * C_DIM + c4 * 4);
        s[0] += v.x; s2[0] += v.x * v.x;
        s[1] += v.y; s2[1] += v.y * v.y;
        s[2] += v.z; s2[2] += v.z * v.z;
        s[3] += v.w; s2[3] += v.w * v.w;
    }
#pragma unroll
    for (int off = 1; off < 64; off <<= 1) {
#pragma unroll
        for (int c = 0; c < 4; ++c) {
            s[c]  += __shfl_xor(s[c],  off, 64);
            s2[c] += __shfl_xor(s2[c], off, 64);
        }
    }
    __shared__ float red[4][8];
    int w = tid >> 6;
    if ((tid & 63) == 0) {
#pragma unroll
        for (int c = 0; c < 4; ++c) { red[w][c] = s[c]; red[w][4 + c] = s2[c]; }
    }
    __syncthreads();
    if (tid == 0) {
#pragma unroll
        for (int c = 0; c < 4; ++c) {
            float fs = red[0][c] + red[1][c] + red[2][c] + red[3][c];
            float fs2 = red[0][4 + c] + red[1][4 + c] + red[2][4 + c] + red[3][4 + c];
            int ch = c4 * 4 + c;
            float mean = fs / N_NODES;
            float var = fs2 / N_NODES - mean * mean;
            float rstd = rsqrtf(var + 1e-5f);
            float scale = g[ch] * rstd;
            ss[ch] = scale;
            ss[C_DIM + ch] = b[ch] - mean * scale;
        }
    }
}

__global__ __launch_bounds__(256) void combine2(const float* __restrict__ p1,
                                                const float* __restrict__ p2,
                                                const float* __restrict__ ss1,
                                                const float* __restrict__ ss2,
                                                float* __restrict__ out,
                                                unsigned short* __restrict__ outb) {
    int idx = blockIdx.x * 256 + threadIdx.x;
    int c4 = (idx & 31) * 4;
    float4 v1 = ((const float4*)p1)[idx];
    float4 v2 = ((const float4*)p2)[idx];
    float4 sc1 = *(const float4*)(ss1 + c4), sh1 = *(const float4*)(ss1 + C_DIM + c4);
    float4 sc2 = *(const float4*)(ss2 + c4), sh2 = *(const float4*)(ss2 + C_DIM + c4);
    float4 o;
    o.x = v1.x * sc1.x + sh1.x + v2.x * sc2.x + sh2.x;
    o.y = v1.y * sc1.y + sh1.y + v2.y * sc2.y + sh2.y;
    o.z = v1.z * sc1.z + sh1.z + v2.z * sc2.z + sh2.z;
    o.w = v1.w * sc1.w + sh1.w + v2.w * sc2.w + sh2.w;
    ((float4*)out)[idx] = o;
    ushort4 ub;
    ub.x = f2bf(o.x); ub.y = f2bf(o.y); ub.z = f2bf(o.z); ub.w = f2bf(o.w);
    *(ushort4*)(outb + (size_t)idx * 4) = ub;
}

__global__ __launch_bounds__(256) void bn_apply(const float* __restrict__ p,
                                                const float* __restrict__ ss,
                                                float* __restrict__ out,
                                                unsigned short* __restrict__ outb) {
    int idx = blockIdx.x * 256 + threadIdx.x;
    int c4 = (idx & 31) * 4;
    float4 v = ((const float4*)p)[idx];
    float4 sc = *(const float4*)(ss + c4), sh = *(const float4*)(ss + C_DIM + c4);
    float4 o;
    o.x = v.x * sc.x + sh.x;
    o.y = v.y * sc.y + sh.y;
    o.z = v.z * sc.z + sh.z;
    o.w = v.w * sc.w + sh.w;
    ((float4*)out)[idx] = o;
    ushort4 ub;
    ub.x = f2bf(o.x); ub.y = f2bf(o.y); ub.z = f2bf(o.z); ub.w = f2bf(o.w);
    *(ushort4*)(outb + (size_t)idx * 4) = ub;
}

// ---------------------------------------------------------------------------
// head layer 1 (fp32, small)
// ---------------------------------------------------------------------------
template <int K>
__global__ __launch_bounds__(256) void gemm_f32(const float* __restrict__ A,
                                                const float* __restrict__ W,
                                                const float* __restrict__ bias,
                                                float* __restrict__ out,
                                                const int J, const int relu) {
    __shared__ __align__(16) float As[64 * 132];
    __shared__ __align__(16) float Ws[64 * 132];
    const int tid = threadIdx.x;
    const int ct = blockIdx.x, rt = blockIdx.y;
    const int tc = tid & 15, tr = tid >> 4;
    float acc[4][4] = {};

    for (int kc = 0; kc < K; kc += 128) {
        if (kc) __syncthreads();
#pragma unroll
        for (int i = 0; i < 8; ++i) {
            int idx = tid + i * 256;
            int r = idx >> 5, kq = idx & 31;
            *(float4*)(As + r * 132 + kq * 4) =
                *(const float4*)(A + (size_t)(rt * 64 + r) * K + kc + kq * 4);
            *(float4*)(Ws + r * 132 + kq * 4) =
                *(const float4*)(W + (size_t)(ct * 64 + r) * K + kc + kq * 4);
        }
        __syncthreads();
#pragma unroll 4
        for (int k4 = 0; k4 < 32; ++k4) {
            float4 a[4], w[4];
#pragma unroll
            for (int i = 0; i < 4; ++i) a[i] = *(const float4*)(As + (tr * 4 + i) * 132 + k4 * 4);
#pragma unroll
            for (int j = 0; j < 4; ++j) w[j] = *(const float4*)(Ws + (tc * 4 + j) * 132 + k4 * 4);
#pragma unroll
            for (int i = 0; i < 4; ++i)
#pragma unroll
                for (int j = 0; j < 4; ++j)
                    acc[i][j] += a[i].x * w[j].x + a[i].y * w[j].y +
                                 a[i].z * w[j].z + a[i].w * w[j].w;
        }
    }

#pragma unroll
    for (int i = 0; i < 4; ++i) {
        int row = rt * 64 + tr * 4 + i;
        float4 o4;
        float* po = (float*)&o4;
#pragma unroll
        for (int j = 0; j < 4; ++j) {
            int col = ct * 64 + tc * 4 + j;
            float v = acc[i][j] + bias[col];
            if (relu) v = fmaxf(v, 0.f);
            po[j] = v;
        }
        *(float4*)(out + (size_t)row * J + ct * 64 + tc * 4) = o4;
    }
}

__global__ __launch_bounds__(256) void head23(const float* __restrict__ hh1,
                                              const float* __restrict__ w2,
                                              const float* __restrict__ b2,
                                              const float* __restrict__ w3,
                                              const float* __restrict__ b3,
                                              float* __restrict__ out) {
    int n = blockIdx.x * 256 + threadIdx.x;
    float4 r[16];
#pragma unroll
    for (int q = 0; q < 16; ++q) r[q] = *(const float4*)(hh1 + (size_t)n * 64 + q * 4);
    float acc = b3[0];
#pragma unroll 4
    for (int j = 0; j < 32; ++j) {
        float sv = b2[j];
#pragma unroll
        for (int q = 0; q < 16; ++q) {
            float4 wr = *(const float4*)(w2 + j * 64 + q * 4);
            sv += r[q].x * wr.x + r[q].y * wr.y + r[q].z * wr.z + r[q].w * wr.w;
        }
        acc += fmaxf(sv, 0.f) * w3[j];
    }
    out[n] = acc;
}

// ---------------------------------------------------------------------------
extern "C" void kernel_launch(void* const* d_in, const int* in_sizes, int n_in,
                              void* d_out, int out_size, void* d_ws, size_t ws_size,
                              hipStream_t stream) {
    (void)in_sizes; (void)n_in; (void)out_size; (void)ws_size;
    const float* x_in   = (const float*)d_in[0];
    const int*   ei     = (const int*)d_in[1];
    const float* gin_w1 = (const float*)d_in[2];
    const float* gin_b1 = (const float*)d_in[3];
    const float* gin_w2 = (const float*)d_in[4];
    const float* gin_b2 = (const float*)d_in[5];
    const float* ain_w  = (const float*)d_in[6];
    const float* ain_b  = (const float*)d_in[7];
    const float* aout_w = (const float*)d_in[8];
    const float* aout_b = (const float*)d_in[9];
    const float* n1_g   = (const float*)d_in[10];
    const float* n1_b   = (const float*)d_in[11];
    const float* n2_g   = (const float*)d_in[12];
    const float* n2_b   = (const float*)d_in[13];
    const float* n3_g   = (const float*)d_in[14];
    const float* n3_b   = (const float*)d_in[15];
    const float* mlp_w1 = (const float*)d_in[16];
    const float* mlp_b1 = (const float*)d_in[17];
    const float* mlp_w2 = (const float*)d_in[18];
    const float* mlp_b2 = (const float*)d_in[19];
    const float* h_w1   = (const float*)d_in[20];
    const float* h_b1   = (const float*)d_in[21];
    const float* h_w2   = (const float*)d_in[22];
    const float* h_b2   = (const float*)d_in[23];
    const float* h_w3   = (const float*)d_in[24];
    const float* h_b3   = (const float*)d_in[25];

    float* f = (float*)d_ws;
    float* g1   = f;                 // c0; m3 aliases (g1 dead after combine2)
    float* m3   = f;
    float* a2   = f + 1 * (size_t)NC;  // c1; hh1 aliases after layers
    float* hh1  = f + 1 * (size_t)NC;
    float* hbuf = f + 2 * (size_t)NC;
    float* xA   = f + 3 * (size_t)NC;
    float* xB   = f + 4 * (size_t)NC;
    unsigned short* R1  = (unsigned short*)(f + 5 * (size_t)NC);  // 3 NCu
    unsigned short* hsum_bf = R1;
    unsigned short* t1_bf   = R1 + (size_t)NCu;
    unsigned short* Qb      = R1;
    unsigned short* Kb      = R1 + (size_t)NCu;
    unsigned short* VT      = R1 + 2 * (size_t)NCu;
    unsigned short* t2_bf   = R1;
    unsigned short* R2      = R1 + 3 * (size_t)NCu;
    unsigned short* ao_bf   = R2;
    unsigned short* hbuf_bf = R2;
    unsigned short* xbf     = R2 + (size_t)NCu;
    unsigned short* wbf     = xbf + (size_t)NCu;
    float* ss    = (float*)(wbf + 655360);
    int* ibase    = (int*)(ss + 768);
    int* deg      = ibase;
    int* rowstart = ibase + 4096;
    int* cursor   = ibase + 4096 + 4098;
    int* csr_src  = ibase + 4096 + 4098 + 4096;

    const int OG1 = 0, OG2 = 65536, OAI = 131072, OAO = 327680, OM1 = 393216, OM2 = 524288;

    hipMemsetAsync(deg, 0, 4096 * sizeof(int), stream);
    hist_kernel<<<E_EDGES / 256, 256, 0, stream>>>(ei, deg);
    scan_kernel<<<1, 256, 0, stream>>>(deg, rowstart, cursor);
    fill_kernel<<<E_EDGES / 256, 256, 0, stream>>>(ei, cursor, csr_src);
    wcvt<<<320, 256, 0, stream>>>(gin_w1, gin_w2, ain_w, aout_w, mlp_w1, mlp_w2, wbf);
    x2bf<<<NC / 2048, 256, 0, stream>>>(x_in, xbf);

    for (int i = 0; i < L_LAYERS; ++i) {
        const float* xin = (i == 0) ? x_in : ((i & 1) ? xA : xB);
        float* xout = (i & 1) ? xB : xA;
        const float* gb1 = gin_b1 + (size_t)i * C_DIM;
        const float* gb2 = gin_b2 + (size_t)i * C_DIM;
        const float* aib = ain_b + (size_t)i * 3 * C_DIM;
        const float* aob = aout_b + (size_t)i * C_DIM;
        const float* mb1 = mlp_b1 + (size_t)i * 2 * C_DIM;
        const float* mb2 = mlp_b2 + (size_t)i * C_DIM;

        // GIN branch
        gather_agg<<<N_NODES / 4, 256, 0, stream>>>(xin, rowstart, csr_src, (unsigned int*)hsum_bf);
        gemm_bf<128><<<dim3(2, 256), 256, 0, stream>>>(hsum_bf, wbf + OG1 + (size_t)i * 16384,
                                                       gb1, nullptr, nullptr, t1_bf, 128, 1);
        gemm_bf<128><<<dim3(2, 256), 256, 0, stream>>>(t1_bf, wbf + OG2 + (size_t)i * 16384,
                                                       gb2, xin, g1, nullptr, 128, 0);
        // attention branch
        gemm_qkv_bf<<<dim3(6, 256), 256, 0, stream>>>(xbf, wbf + OAI + (size_t)i * 49152,
                                                      aib, Qb, Kb, VT);
        attn_kernel<<<dim3(N_NODES / 32, H_HEADS), 512, 0, stream>>>(Qb, Kb, VT, ao_bf);
        gemm_bf<128><<<dim3(2, 256), 256, 0, stream>>>(ao_bf, wbf + OAO + (size_t)i * 16384,
                                                       aob, xin, a2, nullptr, 128, 0);
        // norms + combine
        bn_stats2<<<64, 256, 0, stream>>>(g1, n1_g + (size_t)i * C_DIM, n1_b + (size_t)i * C_DIM, ss,
                                          a2, n2_g + (size_t)i * C_DIM, n2_b + (size_t)i * C_DIM, ss + 256);
        combine2<<<512, 256, 0, stream>>>(g1, a2, ss, ss + 256, hbuf, hbuf_bf);
        // MLP
        gemm_bf<128><<<dim3(4, 256), 256, 0, stream>>>(hbuf_bf, wbf + OM1 + (size_t)i * 32768,
                                                       mb1, nullptr, nullptr, t2_bf, 256, 1);
        gemm_bf<256><<<dim3(2, 256), 256, 0, stream>>>(t2_bf, wbf + OM2 + (size_t)i * 32768,
                                                       mb2, hbuf, m3, nullptr, 128, 0);
        bn_stats<<<32, 256, 0, stream>>>(m3, n3_g + (size_t)i * C_DIM, n3_b + (size_t)i * C_DIM, ss + 512);
        bn_apply<<<512, 256, 0, stream>>>(m3, ss + 512, xout, xbf);
    }

    const float* xf = xB;
    gemm_f32<128><<<dim3(1, 64), 256, 0, stream>>>(xf, h_w1, h_b1, hh1, 64, 1);
    head23<<<16, 256, 0, stream>>>(hh1, h_w2, h_b2, h_w3, h_b3, (float*)d_out);
}

// Round 7
// 474.256 us; speedup vs baseline: 3.8265x; 1.0649x over previous
//
#include <hip/hip_runtime.h>

#define N_NODES 4096
#define C_DIM   128
#define L_LAYERS 4
#define E_EDGES 131072
#define H_HEADS 4
#define D_HEAD  32
#define NC      (N_NODES * C_DIM)
#define NCu     (N_NODES * C_DIM)
#define P_STRIDE 136

typedef short bf16x8 __attribute__((ext_vector_type(8)));
typedef float f32x4  __attribute__((ext_vector_type(4)));

__device__ __forceinline__ unsigned short f2bf(float f) {
    unsigned int u = __float_as_uint(f);
    u += 0x7fffu + ((u >> 16) & 1u);
    return (unsigned short)(u >> 16);
}

__device__ __forceinline__ float bf_lo(unsigned int u) { return __uint_as_float(u << 16); }
__device__ __forceinline__ float bf_hi(unsigned int u) { return __uint_as_float(u & 0xffff0000u); }

__device__ __forceinline__ bf16x8 pack8(const float* v) {
    bf16x8 o;
#pragma unroll
    for (int i = 0; i < 8; ++i) o[i] = (short)f2bf(v[i]);
    return o;
}

// ---------------------------------------------------------------------------
// CSR build (once per launch)
// ---------------------------------------------------------------------------
__global__ __launch_bounds__(256) void hist_kernel(const int* __restrict__ ei,
                                                   int* __restrict__ deg) {
    int e = blockIdx.x * 256 + threadIdx.x;
    atomicAdd(&deg[ei[E_EDGES + e]], 1);
}

__global__ __launch_bounds__(256) void scan_kernel(const int* __restrict__ deg,
                                                   int* __restrict__ rowstart,
                                                   int* __restrict__ cursor) {
    __shared__ int ts[256];
    const int tid = threadIdx.x;
    int loc[16];
    int s = 0;
#pragma unroll
    for (int i = 0; i < 16; ++i) { loc[i] = s; s += deg[tid * 16 + i]; }
    ts[tid] = s;
    __syncthreads();
    for (int off = 1; off < 256; off <<= 1) {
        int t = (tid >= off) ? ts[tid - off] : 0;
        __syncthreads();
        if (tid >= off) ts[tid] += t;
        __syncthreads();
    }
    int off0 = ts[tid] - s;
#pragma unroll
    for (int i = 0; i < 16; ++i) {
        int v = off0 + loc[i];
        rowstart[tid * 16 + i] = v;
        cursor[tid * 16 + i] = v;
    }
    if (tid == 255) rowstart[4096] = off0 + s;
}

__global__ __launch_bounds__(256) void fill_kernel(const int* __restrict__ ei,
                                                   int* __restrict__ cursor,
                                                   int* __restrict__ csr_src) {
    int e = blockIdx.x * 256 + threadIdx.x;
    int d = ei[E_EDGES + e];
    int s = ei[e];
    int p = atomicAdd(&cursor[d], 1);
    csr_src[p] = s;
}

// ---------------------------------------------------------------------------
// weight pre-convert fp32 -> bf16
// ---------------------------------------------------------------------------
__global__ __launch_bounds__(256) void wcvt(const float* __restrict__ s0, const float* __restrict__ s1,
                                            const float* __restrict__ s2, const float* __restrict__ s3,
                                            const float* __restrict__ s4, const float* __restrict__ s5,
                                            unsigned short* __restrict__ wbf) {
    int i0 = (blockIdx.x * 256 + threadIdx.x) * 8;
    const float* src; int base;
    if      (i0 < 65536)  { src = s0; base = 0; }
    else if (i0 < 131072) { src = s1; base = 65536; }
    else if (i0 < 327680) { src = s2; base = 131072; }
    else if (i0 < 393216) { src = s3; base = 327680; }
    else if (i0 < 524288) { src = s4; base = 393216; }
    else                  { src = s5; base = 524288; }
    const float* p = src + (i0 - base);
    float t[8];
#pragma unroll
    for (int i = 0; i < 8; ++i) t[i] = p[i];
    *(bf16x8*)(wbf + i0) = pack8(t);
}

__global__ __launch_bounds__(256) void x2bf(const float* __restrict__ x,
                                            unsigned short* __restrict__ xb) {
    int i0 = (blockIdx.x * 256 + threadIdx.x) * 8;
    float t[8];
#pragma unroll
    for (int i = 0; i < 8; ++i) t[i] = x[i0 + i];
    *(bf16x8*)(xb + i0) = pack8(t);
}

// ---------------------------------------------------------------------------
// GIN aggregation from bf16 x: hsum[n] = x[n] + sum_{j in N(n)} x[j] (bf16 out)
// lane owns 2 channels = one packed uint per row.
// ---------------------------------------------------------------------------
__global__ __launch_bounds__(256) void gather_agg(const unsigned short* __restrict__ xb,
                                                  const int* __restrict__ rowstart,
                                                  const int* __restrict__ csr_src,
                                                  unsigned int* __restrict__ hsum) {
    const int node = blockIdx.x * 4 + (threadIdx.x >> 6);
    const int lane = threadIdx.x & 63;
    const unsigned int* xu = (const unsigned int*)xb;   // [N][64] packed bf16x2
    const int beg = rowstart[node], end = rowstart[node + 1];
    unsigned int su = xu[(size_t)node * 64 + lane];
    float ax = bf_lo(su), ay = bf_hi(su);
    float bx = 0.f, by = 0.f;
    int e = beg;
    for (; e + 4 <= end; e += 4) {
        int s0 = csr_src[e], s1 = csr_src[e + 1], s2 = csr_src[e + 2], s3 = csr_src[e + 3];
        unsigned int u0 = xu[(size_t)s0 * 64 + lane];
        unsigned int u1 = xu[(size_t)s1 * 64 + lane];
        unsigned int u2 = xu[(size_t)s2 * 64 + lane];
        unsigned int u3 = xu[(size_t)s3 * 64 + lane];
        ax += bf_lo(u0) + bf_lo(u1); ay += bf_hi(u0) + bf_hi(u1);
        bx += bf_lo(u2) + bf_lo(u3); by += bf_hi(u2) + bf_hi(u3);
    }
    for (; e < end; ++e) {
        unsigned int u0 = xu[(size_t)csr_src[e] * 64 + lane];
        ax += bf_lo(u0); ay += bf_hi(u0);
    }
    float ox = ax + bx, oy = ay + by;
    hsum[(size_t)node * 64 + lane] = (unsigned int)f2bf(ox) | ((unsigned int)f2bf(oy) << 16);
}

// ---------------------------------------------------------------------------
// bf16 MFMA GEMM, LDS-free, 16x16 tile per wave.
// grid (J/64, N/16), 256 thr = 4 waves.
// ---------------------------------------------------------------------------
template <int K>
__global__ __launch_bounds__(256, 8) void gemm_bf(const unsigned short* __restrict__ Abf,
                                                  const unsigned short* __restrict__ Wbf,
                                                  const float* __restrict__ bias,
                                                  const float* __restrict__ resid,
                                                  float* __restrict__ outf,
                                                  unsigned short* __restrict__ outb,
                                                  const int J, const int relu) {
    const int tid = threadIdx.x;
    const int wv = tid >> 6;
    const int lane = tid & 63, lg = lane >> 4, ll = lane & 15;
    const int rowbase = blockIdx.y * 16;
    const int colbase = blockIdx.x * 64 + wv * 16;

    const unsigned short* Ap = Abf + (size_t)(rowbase + ll) * K + lg * 8;
    const unsigned short* Wp = Wbf + (size_t)(colbase + ll) * K + lg * 8;

    f32x4 acc = {0.f, 0.f, 0.f, 0.f};
#pragma unroll
    for (int k = 0; k < K; k += 32) {
        bf16x8 a = *(const bf16x8*)(Ap + k);
        bf16x8 b = *(const bf16x8*)(Wp + k);
        acc = __builtin_amdgcn_mfma_f32_16x16x32_bf16(a, b, acc, 0, 0, 0);
    }

    const int col = colbase + ll;
    const float bi = bias[col];
#pragma unroll
    for (int r = 0; r < 4; ++r) {
        const int row = rowbase + lg * 4 + r;
        float v = acc[r] + bi;
        if (resid) v += resid[(size_t)row * J + col];
        if (relu) v = fmaxf(v, 0.f);
        if (outf) outf[(size_t)row * J + col] = v;
        if (outb) outb[(size_t)row * J + col] = f2bf(v);
    }
}

// ---------------------------------------------------------------------------
// QKV GEMM with layout epilogue: Qb [H][N][32] (pre-scaled), Kb [H][N][32],
// VT [H][32][N].  grid (6, 256).
// ---------------------------------------------------------------------------
__global__ __launch_bounds__(256, 8) void gemm_qkv_bf(const unsigned short* __restrict__ Abf,
                                                      const unsigned short* __restrict__ Wbf,
                                                      const float* __restrict__ bias,
                                                      unsigned short* __restrict__ Qb,
                                                      unsigned short* __restrict__ Kb,
                                                      unsigned short* __restrict__ VT) {
    const int tid = threadIdx.x;
    const int wv = tid >> 6;
    const int lane = tid & 63, lg = lane >> 4, ll = lane & 15;
    const int rowbase = blockIdx.y * 16;
    const int colbase = blockIdx.x * 64 + wv * 16;

    const unsigned short* Ap = Abf + (size_t)(rowbase + ll) * 128 + lg * 8;
    const unsigned short* Wp = Wbf + (size_t)(colbase + ll) * 128 + lg * 8;

    f32x4 acc = {0.f, 0.f, 0.f, 0.f};
#pragma unroll
    for (int k = 0; k < 128; k += 32) {
        bf16x8 a = *(const bf16x8*)(Ap + k);
        bf16x8 b = *(const bf16x8*)(Wp + k);
        acc = __builtin_amdgcn_mfma_f32_16x16x32_bf16(a, b, acc, 0, 0, 0);
    }

    const float qsc = 0.25506973f;  // (1/sqrt(32)) * log2(e)
    const int col = colbase + ll;
    const float bi = bias[col];
#pragma unroll
    for (int r = 0; r < 4; ++r) {
        const int row = rowbase + lg * 4 + r;
        float v = acc[r] + bi;
        if (col < 128) {
            int hh = col >> 5, d = col & 31;
            Qb[((size_t)hh * N_NODES + row) * D_HEAD + d] = f2bf(v * qsc);
        } else if (col < 256) {
            int c2 = col - 128, hh = c2 >> 5, d = c2 & 31;
            Kb[((size_t)hh * N_NODES + row) * D_HEAD + d] = f2bf(v);
        } else {
            int c2 = col - 256, hh = c2 >> 5, d = c2 & 31;
            VT[((size_t)hh * D_HEAD + d) * N_NODES + row] = f2bf(v);
        }
    }
}

// ---------------------------------------------------------------------------
// Flash attention v4: grid (N/32, H), 512 thr = 8 waves (R6, unchanged).
// ---------------------------------------------------------------------------
__global__ __launch_bounds__(512, 4) void attn_kernel(const unsigned short* __restrict__ Qb,
                                                      const unsigned short* __restrict__ Kb,
                                                      const unsigned short* __restrict__ VT,
                                                      unsigned short* __restrict__ ob) {
    __shared__ __align__(16) unsigned short Pl[8 * 32 * P_STRIDE];
    float (*Ouns)[32][33] = (float (*)[32][33])(void*)Pl;
    float (*Llp)[32] = (float (*)[32])(void*)(Pl + 8 * 32 * 33 * 2);

    const int h   = blockIdx.y;
    const int q0  = blockIdx.x * 32;
    const int tid = threadIdx.x;
    const int wv  = tid >> 6;
    const int lane = tid & 63;
    const int lg  = lane >> 4;
    const int ll  = lane & 15;

    const unsigned short* Qh = Qb + ((size_t)h * N_NODES + q0) * D_HEAD;
    const unsigned short* Kh = Kb + (size_t)h * N_NODES * D_HEAD;
    const unsigned short* Vh = VT + (size_t)h * D_HEAD * N_NODES;

    bf16x8 qf0 = *(const bf16x8*)(Qh + ll * D_HEAD + lg * 8);
    bf16x8 qf1 = *(const bf16x8*)(Qh + (16 + ll) * D_HEAD + lg * 8);

    f32x4 oacc00 = {0.f,0.f,0.f,0.f}, oacc01 = {0.f,0.f,0.f,0.f};
    f32x4 oacc10 = {0.f,0.f,0.f,0.f}, oacc11 = {0.f,0.f,0.f,0.f};
    float l0[4] = {0.f,0.f,0.f,0.f}, l1[4] = {0.f,0.f,0.f,0.f};

    unsigned short* Pw = Pl + wv * (32 * P_STRIDE);
    const int k0 = wv * (N_NODES / 8);

    for (int t = 0; t < (N_NODES / 8) / 128; ++t) {
        const int kt = k0 + t * 128;

        float s0[8][4], s1[8][4];
#pragma unroll
        for (int kc = 0; kc < 8; ++kc) {
            bf16x8 kf = *(const bf16x8*)(Kh + (size_t)(kt + kc * 16 + ll) * D_HEAD + lg * 8);
            f32x4 z = {0.f, 0.f, 0.f, 0.f};
            f32x4 d0 = __builtin_amdgcn_mfma_f32_16x16x32_bf16(qf0, kf, z, 0, 0, 0);
            f32x4 d1 = __builtin_amdgcn_mfma_f32_16x16x32_bf16(qf1, kf, z, 0, 0, 0);
#pragma unroll
            for (int r = 0; r < 4; ++r) { s0[kc][r] = d0[r]; s1[kc][r] = d1[r]; }
        }

#pragma unroll
        for (int r = 0; r < 4; ++r) {
            float a = 0.f, b = 0.f;
#pragma unroll
            for (int kc = 0; kc < 8; ++kc) {
                float p0 = exp2f(s0[kc][r]); s0[kc][r] = p0; a += p0;
                float p1 = exp2f(s1[kc][r]); s1[kc][r] = p1; b += p1;
            }
#pragma unroll
            for (int off = 1; off < 16; off <<= 1) {
                a += __shfl_xor(a, off, 64);
                b += __shfl_xor(b, off, 64);
            }
            l0[r] += a;
            l1[r] += b;
        }

#pragma unroll
        for (int kc = 0; kc < 8; ++kc)
#pragma unroll
            for (int r = 0; r < 4; ++r) {
                Pw[(lg * 4 + r) * P_STRIDE + kc * 16 + ll]      = f2bf(s0[kc][r]);
                Pw[(16 + lg * 4 + r) * P_STRIDE + kc * 16 + ll] = f2bf(s1[kc][r]);
            }
        asm volatile("" ::: "memory");

#pragma unroll
        for (int kc2 = 0; kc2 < 4; ++kc2) {
            bf16x8 va = *(const bf16x8*)(Vh + (size_t)ll * N_NODES + kt + kc2 * 32 + lg * 8);
            bf16x8 vb = *(const bf16x8*)(Vh + (size_t)(16 + ll) * N_NODES + kt + kc2 * 32 + lg * 8);
            bf16x8 pf0 = *(const bf16x8*)(Pw + ll * P_STRIDE + kc2 * 32 + lg * 8);
            bf16x8 pf1 = *(const bf16x8*)(Pw + (16 + ll) * P_STRIDE + kc2 * 32 + lg * 8);
            oacc00 = __builtin_amdgcn_mfma_f32_16x16x32_bf16(pf0, va, oacc00, 0, 0, 0);
            oacc01 = __builtin_amdgcn_mfma_f32_16x16x32_bf16(pf0, vb, oacc01, 0, 0, 0);
            oacc10 = __builtin_amdgcn_mfma_f32_16x16x32_bf16(pf1, va, oacc10, 0, 0, 0);
            oacc11 = __builtin_amdgcn_mfma_f32_16x16x32_bf16(pf1, vb, oacc11, 0, 0, 0);
        }
    }

    __syncthreads();

#pragma unroll
    for (int r = 0; r < 4; ++r) {
        Ouns[wv][lg * 4 + r][ll]           = oacc00[r];
        Ouns[wv][lg * 4 + r][16 + ll]      = oacc01[r];
        Ouns[wv][16 + lg * 4 + r][ll]      = oacc10[r];
        Ouns[wv][16 + lg * 4 + r][16 + ll] = oacc11[r];
    }
    if (ll == 0) {
#pragma unroll
        for (int r = 0; r < 4; ++r) {
            Llp[wv][lg * 4 + r]      = l0[r];
            Llp[wv][16 + lg * 4 + r] = l1[r];
        }
    }
    __syncthreads();

    {
        const int row = tid >> 4, col = tid & 15;
        float L = 0.f, oa = 0.f, obv = 0.f;
#pragma unroll
        for (int w = 0; w < 8; ++w) {
            L   += Llp[w][row];
            oa  += Ouns[w][row][col];
            obv += Ouns[w][row][16 + col];
        }
        float inv = 1.f / L;
        ob[(size_t)(q0 + row) * C_DIM + h * D_HEAD + col]      = f2bf(oa * inv);
        ob[(size_t)(q0 + row) * C_DIM + h * D_HEAD + 16 + col] = f2bf(obv * inv);
    }
}

// ---------------------------------------------------------------------------
// fused double BatchNorm stats
// ---------------------------------------------------------------------------
__global__ __launch_bounds__(256) void bn_stats2(const float* __restrict__ in1,
                                                 const float* __restrict__ g1v,
                                                 const float* __restrict__ b1v,
                                                 float* __restrict__ ss1,
                                                 const float* __restrict__ in2,
                                                 const float* __restrict__ g2v,
                                                 const float* __restrict__ b2v,
                                                 float* __restrict__ ss2) {
    const int which = blockIdx.x >> 5;
    const int c4 = blockIdx.x & 31;
    const float* in = which ? in2 : in1;
    const float* g  = which ? g2v : g1v;
    const float* b  = which ? b2v : b1v;
    float* ss       = which ? ss2 : ss1;
    const int tid = threadIdx.x;
    float s[4] = {0.f,0.f,0.f,0.f}, s2[4] = {0.f,0.f,0.f,0.f};
    for (int r = tid; r < N_NODES; r += 256) {
        float4 v = *(const float4*)(in + (size_t)r * C_DIM + c4 * 4);
        s[0] += v.x; s2[0] += v.x * v.x;
        s[1] += v.y; s2[1] += v.y * v.y;
        s[2] += v.z; s2[2] += v.z * v.z;
        s[3] += v.w; s2[3] += v.w * v.w;
    }
#pragma unroll
    for (int off = 1; off < 64; off <<= 1) {
#pragma unroll
        for (int c = 0; c < 4; ++c) {
            s[c]  += __shfl_xor(s[c],  off, 64);
            s2[c] += __shfl_xor(s2[c], off, 64);
        }
    }
    __shared__ float red[4][8];
    int w = tid >> 6;
    if ((tid & 63) == 0) {
#pragma unroll
        for (int c = 0; c < 4; ++c) { red[w][c] = s[c]; red[w][4 + c] = s2[c]; }
    }
    __syncthreads();
    if (tid == 0) {
#pragma unroll
        for (int c = 0; c < 4; ++c) {
            float fs = red[0][c] + red[1][c] + red[2][c] + red[3][c];
            float fs2 = red[0][4 + c] + red[1][4 + c] + red[2][4 + c] + red[3][4 + c];
            int ch = c4 * 4 + c;
            float mean = fs / N_NODES;
            float var = fs2 / N_NODES - mean * mean;
            float rstd = rsqrtf(var + 1e-5f);
            float scale = g[ch] * rstd;
            ss[ch] = scale;
            ss[C_DIM + ch] = b[ch] - mean * scale;
        }
    }
}

__global__ __launch_bounds__(256) void bn_stats(const float* __restrict__ in,
                                                const float* __restrict__ g,
                                                const float* __restrict__ b,
                                                float* __restrict__ ss) {
    const int c4 = blockIdx.x;
    const int tid = threadIdx.x;
    float s[4] = {0.f,0.f,0.f,0.f}, s2[4] = {0.f,0.f,0.f,0.f};
    for (int r = tid; r < N_NODES; r += 256) {
        float4 v = *(const float4*)(in + (size_t)r * C_DIM + c4 * 4);
        s[0] += v.x; s2[0] += v.x * v.x;
        s[1] += v.y; s2[1] += v.y * v.y;
        s[2] += v.z; s2[2] += v.z * v.z;
        s[3] += v.w; s2[3] += v.w * v.w;
    }
#pragma unroll
    for (int off = 1; off < 64; off <<= 1) {
#pragma unroll
        for (int c = 0; c < 4; ++c) {
            s[c]  += __shfl_xor(s[c],  off, 64);
            s2[c] += __shfl_xor(s2[c], off, 64);
        }
    }
    __shared__ float red[4][8];
    int w = tid >> 6;
    if ((tid & 63) == 0) {
#pragma unroll
        for (int c = 0; c < 4; ++c) { red[w][c] = s[c]; red[w][4 + c] = s2[c]; }
    }
    __syncthreads();
    if (tid == 0) {
#pragma unroll
        for (int c = 0; c < 4; ++c) {
            float fs = red[0][c] + red[1][c] + red[2][c] + red[3][c];
            float fs2 = red[0][4 + c] + red[1][4 + c] + red[2][4 + c] + red[3][4 + c];
            int ch = c4 * 4 + c;
            float mean = fs / N_NODES;
            float var = fs2 / N_NODES - mean * mean;
            float rstd = rsqrtf(var + 1e-5f);
            float scale = g[ch] * rstd;
            ss[ch] = scale;
            ss[C_DIM + ch] = b[ch] - mean * scale;
        }
    }
}

__global__ __launch_bounds__(256) void combine2(const float* __restrict__ p1,
                                                const float* __restrict__ p2,
                                                const float* __restrict__ ss1,
                                                const float* __restrict__ ss2,
                                                float* __restrict__ out,
                                                unsigned short* __restrict__ outb) {
    int idx = blockIdx.x * 256 + threadIdx.x;
    int c4 = (idx & 31) * 4;
    float4 v1 = ((const float4*)p1)[idx];
    float4 v2 = ((const float4*)p2)[idx];
    float4 sc1 = *(const float4*)(ss1 + c4), sh1 = *(const float4*)(ss1 + C_DIM + c4);
    float4 sc2 = *(const float4*)(ss2 + c4), sh2 = *(const float4*)(ss2 + C_DIM + c4);
    float4 o;
    o.x = v1.x * sc1.x + sh1.x + v2.x * sc2.x + sh2.x;
    o.y = v1.y * sc1.y + sh1.y + v2.y * sc2.y + sh2.y;
    o.z = v1.z * sc1.z + sh1.z + v2.z * sc2.z + sh2.z;
    o.w = v1.w * sc1.w + sh1.w + v2.w * sc2.w + sh2.w;
    ((float4*)out)[idx] = o;
    ushort4 ub;
    ub.x = f2bf(o.x); ub.y = f2bf(o.y); ub.z = f2bf(o.z); ub.w = f2bf(o.w);
    *(ushort4*)(outb + (size_t)idx * 4) = ub;
}

__global__ __launch_bounds__(256) void bn_apply(const float* __restrict__ p,
                                                const float* __restrict__ ss,
                                                float* __restrict__ out,
                                                unsigned short* __restrict__ outb) {
    int idx = blockIdx.x * 256 + threadIdx.x;
    int c4 = (idx & 31) * 4;
    float4 v = ((const float4*)p)[idx];
    float4 sc = *(const float4*)(ss + c4), sh = *(const float4*)(ss + C_DIM + c4);
    float4 o;
    o.x = v.x * sc.x + sh.x;
    o.y = v.y * sc.y + sh.y;
    o.z = v.z * sc.z + sh.z;
    o.w = v.w * sc.w + sh.w;
    ((float4*)out)[idx] = o;
    ushort4 ub;
    ub.x = f2bf(o.x); ub.y = f2bf(o.y); ub.z = f2bf(o.z); ub.w = f2bf(o.w);
    *(ushort4*)(outb + (size_t)idx * 4) = ub;
}

// ---------------------------------------------------------------------------
// Fused head MLP: x[4096][128] -> relu(W1) -> relu(W2) -> W3 -> out[4096]
// grid 512, 256 thr; block = 8 nodes, 32 threads/node. All fp32.
// ---------------------------------------------------------------------------
__global__ __launch_bounds__(256) void head_fused(const float* __restrict__ x,
                                                  const float* __restrict__ w1,
                                                  const float* __restrict__ b1,
                                                  const float* __restrict__ w2,
                                                  const float* __restrict__ b2,
                                                  const float* __restrict__ w3,
                                                  const float* __restrict__ b3,
                                                  float* __restrict__ out) {
    __shared__ __align__(16) float xs[8][128];
    __shared__ __align__(16) float hs[8][64];
    const int tid = threadIdx.x;
    const int n = tid >> 5;       // node within block
    const int g = tid & 31;
    const int node0 = blockIdx.x * 8;

    // stage x rows: 256 thr x 1 float4 = 8 x 128
    {
        int r = tid >> 5, q = tid & 31;
        *(float4*)(&xs[r][q * 4]) = *(const float4*)(x + (size_t)(node0 + r) * 128 + q * 4);
    }
    __syncthreads();

    // h1: 2 cols per thread (c = g, g+32)
    {
        float acc0 = b1[g], acc1 = b1[g + 32];
        const float* wa = w1 + (size_t)g * 128;
        const float* wb = w1 + (size_t)(g + 32) * 128;
#pragma unroll 8
        for (int k = 0; k < 128; k += 4) {
            float4 xv = *(const float4*)(&xs[n][k]);
            float4 va = *(const float4*)(wa + k);
            float4 vb = *(const float4*)(wb + k);
            acc0 += xv.x * va.x + xv.y * va.y + xv.z * va.z + xv.w * va.w;
            acc1 += xv.x * vb.x + xv.y * vb.y + xv.z * vb.z + xv.w * vb.w;
        }
        hs[n][g]      = fmaxf(acc0, 0.f);
        hs[n][g + 32] = fmaxf(acc1, 0.f);
    }
    __syncthreads();

    // h2 col g -> * w3[g] -> reduce over 32 lanes
    {
        float acc = b2[g];
        const float* wr = w2 + (size_t)g * 64;
#pragma unroll 8
        for (int k = 0; k < 64; k += 4) {
            float4 hv = *(const float4*)(&hs[n][k]);
            float4 wv = *(const float4*)(wr + k);
            acc += hv.x * wv.x + hv.y * wv.y + hv.z * wv.z + hv.w * wv.w;
        }
        float t = fmaxf(acc, 0.f) * w3[g];
#pragma unroll
        for (int off = 1; off < 32; off <<= 1) t += __shfl_xor(t, off, 64);
        if (g == 0) out[node0 + n] = t + b3[0];
    }
}

// ---------------------------------------------------------------------------
extern "C" void kernel_launch(void* const* d_in, const int* in_sizes, int n_in,
                              void* d_out, int out_size, void* d_ws, size_t ws_size,
                              hipStream_t stream) {
    (void)in_sizes; (void)n_in; (void)out_size; (void)ws_size;
    const float* x_in   = (const float*)d_in[0];
    const int*   ei     = (const int*)d_in[1];
    const float* gin_w1 = (const float*)d_in[2];
    const float* gin_b1 = (const float*)d_in[3];
    const float* gin_w2 = (const float*)d_in[4];
    const float* gin_b2 = (const float*)d_in[5];
    const float* ain_w  = (const float*)d_in[6];
    const float* ain_b  = (const float*)d_in[7];
    const float* aout_w = (const float*)d_in[8];
    const float* aout_b = (const float*)d_in[9];
    const float* n1_g   = (const float*)d_in[10];
    const float* n1_b   = (const float*)d_in[11];
    const float* n2_g   = (const float*)d_in[12];
    const float* n2_b   = (const float*)d_in[13];
    const float* n3_g   = (const float*)d_in[14];
    const float* n3_b   = (const float*)d_in[15];
    const float* mlp_w1 = (const float*)d_in[16];
    const float* mlp_b1 = (const float*)d_in[17];
    const float* mlp_w2 = (const float*)d_in[18];
    const float* mlp_b2 = (const float*)d_in[19];
    const float* h_w1   = (const float*)d_in[20];
    const float* h_b1   = (const float*)d_in[21];
    const float* h_w2   = (const float*)d_in[22];
    const float* h_b2   = (const float*)d_in[23];
    const float* h_w3   = (const float*)d_in[24];
    const float* h_b3   = (const float*)d_in[25];

    float* f = (float*)d_ws;
    float* g1   = f;                 // c0; m3 aliases (g1 dead after combine2)
    float* m3   = f;
    float* a2   = f + 1 * (size_t)NC;
    float* hbuf = f + 2 * (size_t)NC;
    float* xA   = f + 3 * (size_t)NC;
    float* xB   = f + 4 * (size_t)NC;
    unsigned short* R1  = (unsigned short*)(f + 5 * (size_t)NC);  // 3 NCu
    unsigned short* hsum_bf = R1;
    unsigned short* t1_bf   = R1 + (size_t)NCu;
    unsigned short* Qb      = R1;
    unsigned short* Kb      = R1 + (size_t)NCu;
    unsigned short* VT      = R1 + 2 * (size_t)NCu;
    unsigned short* t2_bf   = R1;
    unsigned short* R2      = R1 + 3 * (size_t)NCu;
    unsigned short* ao_bf   = R2;
    unsigned short* hbuf_bf = R2;
    unsigned short* xbf     = R2 + (size_t)NCu;
    unsigned short* wbf     = xbf + (size_t)NCu;
    float* ss    = (float*)(wbf + 655360);
    int* ibase    = (int*)(ss + 768);
    int* deg      = ibase;
    int* rowstart = ibase + 4096;
    int* cursor   = ibase + 4096 + 4098;
    int* csr_src  = ibase + 4096 + 4098 + 4096;

    const int OG1 = 0, OG2 = 65536, OAI = 131072, OAO = 327680, OM1 = 393216, OM2 = 524288;

    hipMemsetAsync(deg, 0, 4096 * sizeof(int), stream);
    hist_kernel<<<E_EDGES / 256, 256, 0, stream>>>(ei, deg);
    scan_kernel<<<1, 256, 0, stream>>>(deg, rowstart, cursor);
    fill_kernel<<<E_EDGES / 256, 256, 0, stream>>>(ei, cursor, csr_src);
    wcvt<<<320, 256, 0, stream>>>(gin_w1, gin_w2, ain_w, aout_w, mlp_w1, mlp_w2, wbf);
    x2bf<<<NC / 2048, 256, 0, stream>>>(x_in, xbf);

    for (int i = 0; i < L_LAYERS; ++i) {
        const float* xin = (i == 0) ? x_in : ((i & 1) ? xA : xB);
        float* xout = (i & 1) ? xB : xA;
        const float* gb1 = gin_b1 + (size_t)i * C_DIM;
        const float* gb2 = gin_b2 + (size_t)i * C_DIM;
        const float* aib = ain_b + (size_t)i * 3 * C_DIM;
        const float* aob = aout_b + (size_t)i * C_DIM;
        const float* mb1 = mlp_b1 + (size_t)i * 2 * C_DIM;
        const float* mb2 = mlp_b2 + (size_t)i * C_DIM;

        // GIN branch (gathers bf16 x)
        gather_agg<<<N_NODES / 4, 256, 0, stream>>>(xbf, rowstart, csr_src, (unsigned int*)hsum_bf);
        gemm_bf<128><<<dim3(2, 256), 256, 0, stream>>>(hsum_bf, wbf + OG1 + (size_t)i * 16384,
                                                       gb1, nullptr, nullptr, t1_bf, 128, 1);
        gemm_bf<128><<<dim3(2, 256), 256, 0, stream>>>(t1_bf, wbf + OG2 + (size_t)i * 16384,
                                                       gb2, xin, g1, nullptr, 128, 0);
        // attention branch
        gemm_qkv_bf<<<dim3(6, 256), 256, 0, stream>>>(xbf, wbf + OAI + (size_t)i * 49152,
                                                      aib, Qb, Kb, VT);
        attn_kernel<<<dim3(N_NODES / 32, H_HEADS), 512, 0, stream>>>(Qb, Kb, VT, ao_bf);
        gemm_bf<128><<<dim3(2, 256), 256, 0, stream>>>(ao_bf, wbf + OAO + (size_t)i * 16384,
                                                       aob, xin, a2, nullptr, 128, 0);
        // norms + combine
        bn_stats2<<<64, 256, 0, stream>>>(g1, n1_g + (size_t)i * C_DIM, n1_b + (size_t)i * C_DIM, ss,
                                          a2, n2_g + (size_t)i * C_DIM, n2_b + (size_t)i * C_DIM, ss + 256);
        combine2<<<512, 256, 0, stream>>>(g1, a2, ss, ss + 256, hbuf, hbuf_bf);
        // MLP
        gemm_bf<128><<<dim3(4, 256), 256, 0, stream>>>(hbuf_bf, wbf + OM1 + (size_t)i * 32768,
                                                       mb1, nullptr, nullptr, t2_bf, 256, 1);
        gemm_bf<256><<<dim3(2, 256), 256, 0, stream>>>(t2_bf, wbf + OM2 + (size_t)i * 32768,
                                                       mb2, hbuf, m3, nullptr, 128, 0);
        bn_stats<<<32, 256, 0, stream>>>(m3, n3_g + (size_t)i * C_DIM, n3_b + (size_t)i * C_DIM, ss + 512);
        bn_apply<<<512, 256, 0, stream>>>(m3, ss + 512, xout, xbf);
    }

    const float* xf = xB;  // after layer 3
    head_fused<<<N_NODES / 8, 256, 0, stream>>>(xf, h_w1, h_b1, h_w2, h_b2, h_w3, h_b3,
                                                (float*)d_out);
}